// Round 8
// baseline (407.278 us; speedup 1.0000x reference)
//
#include <hip/hip_runtime.h>
#include <math.h>

#define DIN 128   // D_IN == D_HID == 128
#define NCLS 64
#define SCALE1 64.0f   // hs1 fp8 scale
#define SCALE2 256.0f  // hs2 fp8 scale

typedef __attribute__((ext_vector_type(4))) float  f32x4;
typedef __attribute__((ext_vector_type(2))) float  f32x2;
typedef __attribute__((ext_vector_type(8))) short  bf16x8;   // MFMA A/B frag (4 VGPRs)

__device__ inline unsigned short f2bf(float f) {             // round-to-nearest-even
    unsigned int u = __float_as_uint(f);
    u += 0x7fff + ((u >> 16) & 1);
    return (unsigned short)(u >> 16);
}

// ---------------- W prep: transpose + cast to bf16; zero deg ----------------

__global__ __launch_bounds__(256) void wprep_k(const float* __restrict__ W1,
                                               const float* __restrict__ W2,
                                               unsigned short* __restrict__ wt1,
                                               unsigned short* __restrict__ wt2,
                                               int* __restrict__ deg, int N) {
    int i = blockIdx.x * 256 + threadIdx.x;
    if (i < 128 * 128) { int k = i >> 7, n = i & 127; wt1[n * 128 + k] = f2bf(W1[i]); }
    if (i < 128 * 64)  { int k = i >> 6, n = i & 63;  wt2[n * 128 + k] = f2bf(W2[i]); }
    if (i < N)         deg[i] = 0;
}

// ---------------- direct CSR build: degree count -> scan -> scatter ----------------

__global__ __launch_bounds__(256) void degA_k(const int* __restrict__ ei,
                                              int* __restrict__ deg, int E) {
    int base = blockIdx.x * 2048 + threadIdx.x;
#pragma unroll
    for (int k = 0; k < 8; ++k) {
        int e = base + k * 256;
        if (e < E) atomicAdd(&deg[ei[E + e]], 1);
    }
}

__global__ __launch_bounds__(1024) void scan1_k(const int* __restrict__ deg,
                                                int* __restrict__ sinc,
                                                int* __restrict__ btot, int N) {
    __shared__ int tmp[1024];
    int t = threadIdx.x, i = blockIdx.x * 1024 + t;
    int v = (i < N) ? deg[i] : 0;
    tmp[t] = v; __syncthreads();
    for (int o = 1; o < 1024; o <<= 1) {
        int x = (t >= o) ? tmp[t - o] : 0;
        __syncthreads();
        tmp[t] += x;
        __syncthreads();
    }
    if (i < N) sinc[i] = tmp[t];
    if (t == 1023) btot[blockIdx.x] = tmp[1023];
}

__global__ __launch_bounds__(128) void scan2_k(const int* __restrict__ btot,
                                               int* __restrict__ bex, int NB1) {
    __shared__ int tmp[128];
    int t = threadIdx.x;
    int v = (t < NB1) ? btot[t] : 0;
    tmp[t] = v; __syncthreads();
    for (int o = 1; o < 128; o <<= 1) {
        int x = (t >= o) ? tmp[t - o] : 0;
        __syncthreads();
        tmp[t] += x;
        __syncthreads();
    }
    if (t < NB1) bex[t] = tmp[t] - v;
}

__global__ __launch_bounds__(1024) void scan3_k(const int* __restrict__ deg,
                                                const int* __restrict__ sinc,
                                                const int* __restrict__ bex,
                                                int* __restrict__ off,
                                                int* __restrict__ cur, int N, int E) {
    int t = threadIdx.x, i = blockIdx.x * 1024 + t;
    if (i < N) {
        int ex = sinc[i] - deg[i] + bex[blockIdx.x];
        off[i] = ex;
        cur[i] = ex;
    }
    if (i == N) off[N] = E;
}

// ---------------- smix: edge scatter (blocks < NS) || layer-1 MFMA GEMM ----------------
// scatter: srcs[atomicAdd(&cur[dst])] = src  (per-node regions, byte-disjoint stores)
// mgemm: BM=64 rows/block, BN=128, fp32 A -> bf16 LDS -> MFMA -> fp8 out, dinv inline.

__global__ __launch_bounds__(256) void smix_k(const int* __restrict__ ei,
                                              int* __restrict__ cur,
                                              int* __restrict__ srcs, int E,
                                              const float* __restrict__ A,
                                              const unsigned short* __restrict__ Bt,
                                              const int* __restrict__ deg,
                                              unsigned char* __restrict__ C,
                                              float oscale, int N, int NS) {
    constexpr int LDK = DIN + 8;
    constexpr int BN  = 128;
    __shared__ unsigned short As[64 * LDK];
    __shared__ unsigned short Bs[BN * LDK];

    if ((int)blockIdx.x < NS) {
        int base = blockIdx.x * 2048 + threadIdx.x;
#pragma unroll
        for (int k = 0; k < 8; ++k) {
            int e = base + k * 256;
            if (e < E) {
                int s = ei[e];
                int d = ei[E + e];
                int r = atomicAdd(&cur[d], 1);
                srcs[r] = s;
            }
        }
        return;
    }

    const int tid  = threadIdx.x;
    const int row0 = ((int)blockIdx.x - NS) * 64;

    for (int idx = tid; idx < BN * 16; idx += 256) {
        int n = idx >> 4, c = (idx & 15) << 3;
        *(uint4*)&Bs[n * LDK + c] = *(const uint4*)&Bt[n * DIN + c];
    }
    for (int idx = tid; idx < 64 * 16; idx += 256) {
        int r = idx >> 4, c = (idx & 15) << 3;
        int gr = row0 + r;
        unsigned short v[8];
        if (gr < N) {
            f32x4 a0 = *(const f32x4*)&A[(size_t)gr * DIN + c];
            f32x4 a1 = *(const f32x4*)&A[(size_t)gr * DIN + c + 4];
            v[0] = f2bf(a0.x); v[1] = f2bf(a0.y); v[2] = f2bf(a0.z); v[3] = f2bf(a0.w);
            v[4] = f2bf(a1.x); v[5] = f2bf(a1.y); v[6] = f2bf(a1.z); v[7] = f2bf(a1.w);
        } else {
#pragma unroll
            for (int j = 0; j < 8; ++j) v[j] = 0;
        }
        *(uint4*)&As[r * LDK + c] = *(const uint4*)v;
    }
    __syncthreads();

    const int wave = tid >> 6, lane = tid & 63;
    const int lrow = lane & 15, kq = lane >> 4;
    constexpr int NT = BN / 16;
    f32x4 acc[NT];
#pragma unroll
    for (int t = 0; t < NT; ++t) acc[t] = (f32x4){0.f, 0.f, 0.f, 0.f};

    const unsigned short* Abase = &As[(wave * 16 + lrow) * LDK + kq * 8];
    const unsigned short* Bbase = &Bs[lrow * LDK + kq * 8];
#pragma unroll
    for (int kk = 0; kk < 4; ++kk) {
        bf16x8 a = *(const bf16x8*)(Abase + kk * 32);
#pragma unroll
        for (int t = 0; t < NT; ++t) {
            bf16x8 b = *(const bf16x8*)(Bbase + t * 16 * LDK + kk * 32);
            acc[t] = __builtin_amdgcn_mfma_f32_16x16x32_bf16(a, b, acc[t], 0, 0, 0);
        }
    }

    const int rb = row0 + wave * 16 + kq * 4;
#pragma unroll
    for (int r = 0; r < 4; ++r) {
        int gr = rb + r;
        if (gr < N) {
            float sc2 = rsqrtf(1.0f + (float)deg[gr]) * oscale;
#pragma unroll
            for (int t = 0; t < NT; t += 2) {
                int pk = __builtin_amdgcn_cvt_pk_fp8_f32(acc[t][r] * sc2,
                                                         acc[t + 1][r] * sc2, 0, false);
                C[(size_t)gr * BN + t * 16 + lrow]       = (unsigned char)(pk & 0xff);
                C[(size_t)gr * BN + (t + 1) * 16 + lrow] = (unsigned char)((pk >> 8) & 0xff);
            }
        }
    }
}

__device__ inline void dec8(uint2 v, f32x2& x0, f32x2& x1, f32x2& x2, f32x2& x3) {
    x0 += __builtin_amdgcn_cvt_pk_f32_fp8((int)v.x, false);
    x1 += __builtin_amdgcn_cvt_pk_f32_fp8((int)v.x, true);
    x2 += __builtin_amdgcn_cvt_pk_f32_fp8((int)v.y, false);
    x3 += __builtin_amdgcn_cvt_pk_f32_fp8((int)v.y, true);
}

__device__ inline void dec16(uint4 v, f32x2& x0, f32x2& x1, f32x2& x2, f32x2& x3,
                             f32x2& x4, f32x2& x5, f32x2& x6, f32x2& x7) {
    x0 += __builtin_amdgcn_cvt_pk_f32_fp8((int)v.x, false);
    x1 += __builtin_amdgcn_cvt_pk_f32_fp8((int)v.x, true);
    x2 += __builtin_amdgcn_cvt_pk_f32_fp8((int)v.y, false);
    x3 += __builtin_amdgcn_cvt_pk_f32_fp8((int)v.y, true);
    x4 += __builtin_amdgcn_cvt_pk_f32_fp8((int)v.z, false);
    x5 += __builtin_amdgcn_cvt_pk_f32_fp8((int)v.z, true);
    x6 += __builtin_amdgcn_cvt_pk_f32_fp8((int)v.w, false);
    x7 += __builtin_amdgcn_cvt_pk_f32_fp8((int)v.w, true);
}

// ---------------- fused gather1 + layer-2 GEMM ----------------
// 512 threads / 64 nodes per block. One 8-lane octet per node (fully parallel);
// lane sl covers 16 fp8 cols (one uint4 per edge). LDS 34.8 KB -> 4 blocks/CU;
// launch_bounds forces VGPR<=64 -> 32 waves/CU.

__global__ __launch_bounds__(512, 8) void fuse2_k(const unsigned char* __restrict__ hs,
                                                  const int* __restrict__ off,
                                                  const int* __restrict__ srcs,
                                                  const int* __restrict__ deg,
                                                  const float* __restrict__ b1,
                                                  const unsigned short* __restrict__ Bt,
                                                  unsigned char* __restrict__ C,
                                                  int N) {
    constexpr int LDK = DIN + 8;
    __shared__ unsigned short As[64 * LDK];
    __shared__ unsigned short Bs[NCLS * LDK];
    const int tid  = threadIdx.x;
    const int row0 = blockIdx.x * 64;

    for (int idx = tid; idx < NCLS * 16; idx += 512) {
        int n = idx >> 4, c = (idx & 15) << 3;
        *(uint4*)&Bs[n * LDK + c] = *(const uint4*)&Bt[n * DIN + c];
    }

    // ---- phase 1: octet-per-node gather/aggregate into As ----
    const int oc = tid >> 3;           // octet 0..63 == As row
    const int sl = tid & 7;            // covers fp8 cols 16*sl .. 16*sl+15
    const int node = row0 + oc;
    const uint4* hp = (const uint4*)hs;  // hs1 row = 8 x uint4

    if (node < N) {
        const int beg = off[node], end = off[node + 1];
        f32x2 a0={0.f,0.f},a1={0.f,0.f},a2={0.f,0.f},a3={0.f,0.f};
        f32x2 a4={0.f,0.f},a5={0.f,0.f},a6={0.f,0.f},a7={0.f,0.f};
        int i = beg;
        for (; i + 3 < end; i += 4) {
            unsigned s0 = (unsigned)srcs[i],     s1 = (unsigned)srcs[i + 1];
            unsigned s2 = (unsigned)srcs[i + 2], s3 = (unsigned)srcs[i + 3];
            uint4 v0 = hp[s0 * 8u + sl];
            uint4 v1 = hp[s1 * 8u + sl];
            uint4 v2 = hp[s2 * 8u + sl];
            uint4 v3 = hp[s3 * 8u + sl];
            dec16(v0, a0,a1,a2,a3,a4,a5,a6,a7);
            dec16(v1, a0,a1,a2,a3,a4,a5,a6,a7);
            dec16(v2, a0,a1,a2,a3,a4,a5,a6,a7);
            dec16(v3, a0,a1,a2,a3,a4,a5,a6,a7);
        }
        for (; i < end; ++i) {
            uint4 v = hp[(unsigned)srcs[i] * 8u + sl];
            dec16(v, a0,a1,a2,a3,a4,a5,a6,a7);
        }
        {   // self-loop
            uint4 v = hp[(unsigned)node * 8u + sl];
            dec16(v, a0,a1,a2,a3,a4,a5,a6,a7);
        }
        const float d = rsqrtf(1.0f + (float)deg[node]) * (1.0f / SCALE1);
        const float4 w0 = ((const float4*)b1)[sl * 4 + 0];
        const float4 w1 = ((const float4*)b1)[sl * 4 + 1];
        const float4 w2 = ((const float4*)b1)[sl * 4 + 2];
        const float4 w3 = ((const float4*)b1)[sl * 4 + 3];
        float o0  = fmaxf(fmaf(d, a0.x, w0.x), 0.f);
        float o1  = fmaxf(fmaf(d, a0.y, w0.y), 0.f);
        float o2  = fmaxf(fmaf(d, a1.x, w0.z), 0.f);
        float o3  = fmaxf(fmaf(d, a1.y, w0.w), 0.f);
        float o4  = fmaxf(fmaf(d, a2.x, w1.x), 0.f);
        float o5  = fmaxf(fmaf(d, a2.y, w1.y), 0.f);
        float o6  = fmaxf(fmaf(d, a3.x, w1.z), 0.f);
        float o7  = fmaxf(fmaf(d, a3.y, w1.w), 0.f);
        float o8  = fmaxf(fmaf(d, a4.x, w2.x), 0.f);
        float o9  = fmaxf(fmaf(d, a4.y, w2.y), 0.f);
        float o10 = fmaxf(fmaf(d, a5.x, w2.z), 0.f);
        float o11 = fmaxf(fmaf(d, a5.y, w2.w), 0.f);
        float o12 = fmaxf(fmaf(d, a6.x, w3.x), 0.f);
        float o13 = fmaxf(fmaf(d, a6.y, w3.y), 0.f);
        float o14 = fmaxf(fmaf(d, a7.x, w3.z), 0.f);
        float o15 = fmaxf(fmaf(d, a7.y, w3.w), 0.f);
        uint4 u0, u1;
        u0.x = (unsigned)f2bf(o0)  | ((unsigned)f2bf(o1)  << 16);
        u0.y = (unsigned)f2bf(o2)  | ((unsigned)f2bf(o3)  << 16);
        u0.z = (unsigned)f2bf(o4)  | ((unsigned)f2bf(o5)  << 16);
        u0.w = (unsigned)f2bf(o6)  | ((unsigned)f2bf(o7)  << 16);
        u1.x = (unsigned)f2bf(o8)  | ((unsigned)f2bf(o9)  << 16);
        u1.y = (unsigned)f2bf(o10) | ((unsigned)f2bf(o11) << 16);
        u1.z = (unsigned)f2bf(o12) | ((unsigned)f2bf(o13) << 16);
        u1.w = (unsigned)f2bf(o14) | ((unsigned)f2bf(o15) << 16);
        *(uint4*)&As[oc * LDK + sl * 16]     = u0;
        *(uint4*)&As[oc * LDK + sl * 16 + 8] = u1;
    } else {
        uint4 z = make_uint4(0, 0, 0, 0);
        *(uint4*)&As[oc * LDK + sl * 16]     = z;
        *(uint4*)&As[oc * LDK + sl * 16 + 8] = z;
    }
    __syncthreads();

    // ---- phase 2: As[64x128] @ Bs^T[128x64] -> fp8 C ----
    const int wave = tid >> 6, lane = tid & 63;
    const int ws = wave & 3;           // row stripe (16 rows)
    const int ch = wave >> 2;          // col half (32 cols)
    const int lrow = lane & 15, kq = lane >> 4;
    f32x4 acc0 = (f32x4){0.f,0.f,0.f,0.f};
    f32x4 acc1 = (f32x4){0.f,0.f,0.f,0.f};

    const unsigned short* Abase = &As[(ws * 16 + lrow) * LDK + kq * 8];
    const unsigned short* Bbase = &Bs[(ch * 32 + lrow) * LDK + kq * 8];
#pragma unroll
    for (int kk = 0; kk < 4; ++kk) {
        bf16x8 a  = *(const bf16x8*)(Abase + kk * 32);
        bf16x8 b0 = *(const bf16x8*)(Bbase + kk * 32);
        bf16x8 b1v= *(const bf16x8*)(Bbase + 16 * LDK + kk * 32);
        acc0 = __builtin_amdgcn_mfma_f32_16x16x32_bf16(a, b0,  acc0, 0, 0, 0);
        acc1 = __builtin_amdgcn_mfma_f32_16x16x32_bf16(a, b1v, acc1, 0, 0, 0);
    }

    const int rb = row0 + ws * 16 + kq * 4;
#pragma unroll
    for (int r = 0; r < 4; ++r) {
        int gr = rb + r;
        if (gr < N) {
            float sc2 = rsqrtf(1.0f + (float)deg[gr]) * SCALE2;
            int pk = __builtin_amdgcn_cvt_pk_fp8_f32(acc0[r] * sc2, acc1[r] * sc2, 0, false);
            C[(size_t)gr * NCLS + ch * 32 + lrow]      = (unsigned char)(pk & 0xff);
            C[(size_t)gr * NCLS + ch * 32 + 16 + lrow] = (unsigned char)((pk >> 8) & 0xff);
        }
    }
}

// ---------------- gather layer 2 + log_softmax (fp8 in) ----------------
// one 8-lane octet owns one node; lane sl covers cols 8*sl..8*sl+7. unroll 8.

__global__ __launch_bounds__(256) void gather2_k(const unsigned char* __restrict__ hs,
                                                 const int* __restrict__ off,
                                                 const int* __restrict__ srcs,
                                                 const int* __restrict__ deg,
                                                 const float* __restrict__ b2,
                                                 float* __restrict__ out, int N) {
    const int lane = threadIdx.x & 63;
    const int wave = threadIdx.x >> 6;
    const int o8 = lane >> 3;          // octet 0..7 -> node within wave
    const int sl = lane & 7;           // covers cols 8*sl..8*sl+7
    const int node = blockIdx.x * 32 + wave * 8 + o8;
    if (node >= N) return;
    const int beg = off[node], end = off[node + 1];
    const uint2* hp = (const uint2*)hs;            // row = 8 x uint2
    f32x2 A0 = {0.f,0.f}, A1 = {0.f,0.f}, A2 = {0.f,0.f}, A3 = {0.f,0.f};
    f32x2 C0 = {0.f,0.f}, C1 = {0.f,0.f}, C2 = {0.f,0.f}, C3 = {0.f,0.f};
    int i = beg;
    for (; i + 7 < end; i += 8) {
        unsigned s0 = (unsigned)srcs[i],     s1 = (unsigned)srcs[i + 1];
        unsigned s2 = (unsigned)srcs[i + 2], s3 = (unsigned)srcs[i + 3];
        unsigned s4 = (unsigned)srcs[i + 4], s5 = (unsigned)srcs[i + 5];
        unsigned s6 = (unsigned)srcs[i + 6], s7 = (unsigned)srcs[i + 7];
        uint2 v0 = hp[s0 * 8u + sl];
        uint2 v1 = hp[s1 * 8u + sl];
        uint2 v2 = hp[s2 * 8u + sl];
        uint2 v3 = hp[s3 * 8u + sl];
        uint2 v4 = hp[s4 * 8u + sl];
        uint2 v5 = hp[s5 * 8u + sl];
        uint2 v6 = hp[s6 * 8u + sl];
        uint2 v7 = hp[s7 * 8u + sl];
        dec8(v0, A0, A1, A2, A3);
        dec8(v1, C0, C1, C2, C3);
        dec8(v2, A0, A1, A2, A3);
        dec8(v3, C0, C1, C2, C3);
        dec8(v4, A0, A1, A2, A3);
        dec8(v5, C0, C1, C2, C3);
        dec8(v6, A0, A1, A2, A3);
        dec8(v7, C0, C1, C2, C3);
    }
    for (; i + 3 < end; i += 4) {
        unsigned s0 = (unsigned)srcs[i],     s1 = (unsigned)srcs[i + 1];
        unsigned s2 = (unsigned)srcs[i + 2], s3 = (unsigned)srcs[i + 3];
        uint2 v0 = hp[s0 * 8u + sl];
        uint2 v1 = hp[s1 * 8u + sl];
        uint2 v2 = hp[s2 * 8u + sl];
        uint2 v3 = hp[s3 * 8u + sl];
        dec8(v0, A0, A1, A2, A3);
        dec8(v1, C0, C1, C2, C3);
        dec8(v2, A0, A1, A2, A3);
        dec8(v3, C0, C1, C2, C3);
    }
    for (; i < end; ++i) {
        uint2 v = hp[(unsigned)srcs[i] * 8u + sl];
        dec8(v, A0, A1, A2, A3);
    }
    {   // self-loop
        uint2 v = hp[(unsigned)node * 8u + sl];
        dec8(v, C0, C1, C2, C3);
    }
    A0 += C0; A1 += C1; A2 += C2; A3 += C3;

    float d = rsqrtf(1.0f + (float)deg[node]) * (1.0f / SCALE2);
    float4 ba = ((const float4*)b2)[sl * 2];
    float4 bb = ((const float4*)b2)[sl * 2 + 1];
    float v0 = fmaf(d, A0.x, ba.x);
    float v1 = fmaf(d, A0.y, ba.y);
    float v2 = fmaf(d, A1.x, ba.z);
    float v3 = fmaf(d, A1.y, ba.w);
    float v4 = fmaf(d, A2.x, bb.x);
    float v5 = fmaf(d, A2.y, bb.y);
    float v6 = fmaf(d, A3.x, bb.z);
    float v7 = fmaf(d, A3.y, bb.w);
    float m = fmaxf(fmaxf(fmaxf(v0, v1), fmaxf(v2, v3)), fmaxf(fmaxf(v4, v5), fmaxf(v6, v7)));
#pragma unroll
    for (int mk = 1; mk <= 4; mk <<= 1) m = fmaxf(m, __shfl_xor(m, mk, 64));
    float s = __expf(v0 - m) + __expf(v1 - m) + __expf(v2 - m) + __expf(v3 - m)
            + __expf(v4 - m) + __expf(v5 - m) + __expf(v6 - m) + __expf(v7 - m);
#pragma unroll
    for (int mk = 1; mk <= 4; mk <<= 1) s += __shfl_xor(s, mk, 64);
    float ls = m + __logf(s);
    float4 oa, ob;
    oa.x = v0 - ls; oa.y = v1 - ls; oa.z = v2 - ls; oa.w = v3 - ls;
    ob.x = v4 - ls; ob.y = v5 - ls; ob.z = v6 - ls; ob.w = v7 - ls;
    ((float4*)out)[(unsigned)node * 16u + sl * 2]     = oa;
    ((float4*)out)[(unsigned)node * 16u + sl * 2 + 1] = ob;
}

// ---------------- launch ----------------

extern "C" void kernel_launch(void* const* d_in, const int* in_sizes, int n_in,
                              void* d_out, int out_size, void* d_ws, size_t ws_size,
                              hipStream_t stream) {
    const float* x  = (const float*)d_in[0];
    const int*   ei = (const int*)d_in[1];
    const float* W1 = (const float*)d_in[2];
    const float* b1 = (const float*)d_in[3];
    const float* W2 = (const float*)d_in[4];
    const float* b2 = (const float*)d_in[5];
    float* out = (float*)d_out;

    const int N   = in_sizes[0] / DIN;
    const int E   = in_sizes[1] / 2;
    const int NB1 = (N + 1023) / 1024;       // scan blocks (98)
    const int NS  = (E + 2047) / 2048;       // scatter blocks (782)
    const int NG  = (N + 63) / 64;           // mgemm blocks (1563)

    char* p = (char*)d_ws;
    auto alloc = [&](size_t bytes) { void* r = p; p += (bytes + 255) & ~(size_t)255; return r; };
    int* deg   = (int*)alloc((size_t)N * 4);
    int* off   = (int*)alloc((size_t)(N + 1) * 4);
    int* cur   = (int*)alloc((size_t)N * 4);
    int* srcs  = (int*)alloc((size_t)E * 4);
    int* sinc  = (int*)alloc((size_t)N * 4);
    int* btot  = (int*)alloc(256 * 4);
    int* bex   = (int*)alloc(256 * 4);
    unsigned short* wt1 = (unsigned short*)alloc(128 * 128 * 2);
    unsigned short* wt2 = (unsigned short*)alloc(64 * 128 * 2);
    unsigned char*  hs1 = (unsigned char*)alloc((size_t)N * DIN);   // fp8
    unsigned char*  hs2 = (unsigned char*)alloc((size_t)N * NCLS);  // fp8

    wprep_k<<<(N + 255) / 256, 256, 0, stream>>>(W1, W2, wt1, wt2, deg, N);
    degA_k<<<NS, 256, 0, stream>>>(ei, deg, E);
    scan1_k<<<NB1, 1024, 0, stream>>>(deg, sinc, btot, N);
    scan2_k<<<1, 128, 0, stream>>>(btot, bex, NB1);
    scan3_k<<<NB1, 1024, 0, stream>>>(deg, sinc, bex, off, cur, N, E);
    smix_k<<<NS + NG, 256, 0, stream>>>(ei, cur, srcs, E, x, wt1, deg, hs1, SCALE1, N, NS);
    fuse2_k<<<(N + 63) / 64, 512, 0, stream>>>(hs1, off, srcs, deg, b1, wt2, hs2, N);
    gather2_k<<<(N + 31) / 32, 256, 0, stream>>>(hs2, off, srcs, deg, b2, out, N);
}

// Round 9
// 267.581 us; speedup vs baseline: 1.5221x; 1.5221x over previous
//
#include <hip/hip_runtime.h>
#include <math.h>

#define DIN 128   // D_IN == D_HID == 128
#define NCLS 64
#define BSH  7    // log2(bucket size): 128 dst-nodes per bucket
#define BSZ  128
#define BCAP 2816 // per-bucket capacity: mean 2046, sd ~45 -> +17 sigma
#define SCALE1 64.0f   // hs1 fp8 scale
#define SCALE2 256.0f  // hs2 fp8 scale

typedef __attribute__((ext_vector_type(4))) float  f32x4;
typedef __attribute__((ext_vector_type(2))) float  f32x2;
typedef __attribute__((ext_vector_type(8))) short  bf16x8;   // MFMA A/B frag (4 VGPRs)

__device__ inline unsigned short f2bf(float f) {             // round-to-nearest-even
    unsigned int u = __float_as_uint(f);
    u += 0x7fff + ((u >> 16) & 1);
    return (unsigned short)(u >> 16);
}

// ---------------- W prep: transpose + cast to bf16; zero deg + gcnt ----------------

__global__ __launch_bounds__(256) void wprep_k(const float* __restrict__ W1,
                                               const float* __restrict__ W2,
                                               unsigned short* __restrict__ wt1,
                                               unsigned short* __restrict__ wt2,
                                               int* __restrict__ deg,
                                               int* __restrict__ gcnt, int N, int NB) {
    int i = blockIdx.x * 256 + threadIdx.x;
    if (i < 128 * 128) { int k = i >> 7, n = i & 127; wt1[n * 128 + k] = f2bf(W1[i]); }
    if (i < 128 * 64)  { int k = i >> 6, n = i & 63;  wt2[n * 128 + k] = f2bf(W2[i]); }
    if (i < N)         deg[i] = 0;
    if (i < NB)        gcnt[i] = 0;
}

// ---------------- CSR build phase A: bucket counting sort + per-node degree ----------------
// bucket = dst >> 7 (128 nodes). Also counts deg[dst] so mgemm is independent of binB.

__global__ __launch_bounds__(256) void binA_k(const int* __restrict__ ei,
                                              int* __restrict__ gcnt,
                                              int* __restrict__ deg,
                                              unsigned int* __restrict__ tmp,
                                              int E, int NB) {
    __shared__ int lcnt[1024];
    __shared__ int gpos[1024];
    const int t = threadIdx.x;
    for (int i = t; i < NB; i += 256) lcnt[i] = 0;
    __syncthreads();

    const int base = blockIdx.x * 4096;
    unsigned int pk[16];
    short bk[16], rk[16];
#pragma unroll
    for (int k = 0; k < 16; ++k) {
        int e = base + k * 256 + t;
        if (e < E) {
            int s = ei[e];
            int d = ei[E + e];
            atomicAdd(&deg[d], 1);
            int b = d >> BSH;
            pk[k] = ((unsigned int)s << BSH) | (unsigned int)(d & (BSZ - 1));
            bk[k] = (short)b;
            rk[k] = (short)atomicAdd(&lcnt[b], 1);
        } else {
            bk[k] = -1;
        }
    }
    __syncthreads();
    for (int i = t; i < NB; i += 256)
        gpos[i] = lcnt[i] ? atomicAdd(&gcnt[i], lcnt[i]) : 0;
    __syncthreads();
#pragma unroll
    for (int k = 0; k < 16; ++k) {
        if (bk[k] >= 0) {
            int b = bk[k];
            int pos = gpos[b] + rk[k];
            if (pos < BCAP) tmp[(size_t)b * BCAP + pos] = pk[k];
        }
    }
}

__global__ __launch_bounds__(1024) void scanb_k(const int* __restrict__ gcnt,
                                                int* __restrict__ bbase, int NB) {
    __shared__ int tmp[1024];
    int t = threadIdx.x;
    int v = (t < NB) ? gcnt[t] : 0;
    tmp[t] = v; __syncthreads();
    for (int o = 1; o < 1024; o <<= 1) {
        int x = (t >= o) ? tmp[t - o] : 0;
        __syncthreads();
        tmp[t] += x;
        __syncthreads();
    }
    if (t < NB) bbase[t] = (t == 0) ? 0 : tmp[t - 1];
}

// ---------------- bmix: binB (blocks < NB) || layer-1 MFMA GEMM ----------------
// binB: per-bucket counting sort by dst&127 -> CSR srcs + off. Writes stay within the
// bucket's contiguous ~8KB segment (no write amplification — the round-8 lesson).
// mgemm: BM=64, BN=128, fp32 A -> bf16 LDS -> MFMA -> fp8, rsqrt(1+deg) inline.
// LDS overlaid in one 52224B array so mgemm keeps 3 blocks/CU.

__global__ __launch_bounds__(256) void bmix_k(const unsigned int* __restrict__ tmp,
                                              const int* __restrict__ gcnt,
                                              const int* __restrict__ bbase,
                                              int* __restrict__ off,
                                              int* __restrict__ srcs,
                                              int N, int E, int NB,
                                              const float* __restrict__ A,
                                              const unsigned short* __restrict__ Bt,
                                              const int* __restrict__ deg,
                                              unsigned char* __restrict__ C,
                                              float oscale) {
    constexpr int LDK = DIN + 8;
    constexpr int BN  = 128;
    __shared__ __align__(16) unsigned char raw[64 * LDK * 2 + BN * LDK * 2]; // 52224 B
    const int t = threadIdx.x;

    if ((int)blockIdx.x < NB) {
        // ---- binB path (uses 13.3 KB of raw) ----
        unsigned int* stg  = (unsigned int*)raw;               // BCAP u32 = 11264 B
        int* lcnt = (int*)(raw + BCAP * 4);                    // 128 ints
        int* sc   = lcnt + BSZ;
        int* loff = sc + BSZ;
        int* lcur = loff + BSZ;
        const int b = blockIdx.x;
        int cnt = gcnt[b];
        if (cnt > BCAP) cnt = BCAP;
        const int base = bbase[b];
        if (t < BSZ) { lcnt[t] = 0; lcur[t] = 0; }
        __syncthreads();
        for (int i = t; i < cnt; i += 256) {
            unsigned int v = tmp[(size_t)b * BCAP + i];
            stg[i] = v;
            atomicAdd(&lcnt[v & (BSZ - 1u)], 1);
        }
        __syncthreads();
        if (t < BSZ) sc[t] = lcnt[t];
        __syncthreads();
        for (int o = 1; o < BSZ; o <<= 1) {
            int x = 0;
            if (t < BSZ && t >= o) x = sc[t - o];
            __syncthreads();
            if (t < BSZ) sc[t] += x;
            __syncthreads();
        }
        if (t < BSZ) {
            int excl = (t == 0) ? 0 : sc[t - 1];
            loff[t] = excl;
            int node = b * BSZ + t;
            if (node <= N) off[node] = base + excl;
        }
        __syncthreads();
        for (int i = t; i < cnt; i += 256) {
            unsigned int v = stg[i];
            int l = v & (BSZ - 1u);
            int r = atomicAdd(&lcur[l], 1);
            srcs[base + loff[l] + r] = (int)(v >> BSH);
        }
        return;
    }

    // ---- mgemm path ----
    unsigned short* As = (unsigned short*)raw;                 // 64 x LDK
    unsigned short* Bs = As + 64 * LDK;                        // BN x LDK
    const int row0 = ((int)blockIdx.x - NB) * 64;

    for (int idx = t; idx < BN * 16; idx += 256) {
        int n = idx >> 4, c = (idx & 15) << 3;
        *(uint4*)&Bs[n * LDK + c] = *(const uint4*)&Bt[n * DIN + c];
    }
    for (int idx = t; idx < 64 * 16; idx += 256) {
        int r = idx >> 4, c = (idx & 15) << 3;
        int gr = row0 + r;
        unsigned short v[8];
        if (gr < N) {
            f32x4 a0 = *(const f32x4*)&A[(size_t)gr * DIN + c];
            f32x4 a1 = *(const f32x4*)&A[(size_t)gr * DIN + c + 4];
            v[0] = f2bf(a0.x); v[1] = f2bf(a0.y); v[2] = f2bf(a0.z); v[3] = f2bf(a0.w);
            v[4] = f2bf(a1.x); v[5] = f2bf(a1.y); v[6] = f2bf(a1.z); v[7] = f2bf(a1.w);
        } else {
#pragma unroll
            for (int j = 0; j < 8; ++j) v[j] = 0;
        }
        *(uint4*)&As[r * LDK + c] = *(const uint4*)v;
    }
    __syncthreads();

    const int wave = t >> 6, lane = t & 63;
    const int lrow = lane & 15, kq = lane >> 4;
    constexpr int NT = BN / 16;
    f32x4 acc[NT];
#pragma unroll
    for (int q = 0; q < NT; ++q) acc[q] = (f32x4){0.f, 0.f, 0.f, 0.f};

    const unsigned short* Abase = &As[(wave * 16 + lrow) * LDK + kq * 8];
    const unsigned short* Bbase = &Bs[lrow * LDK + kq * 8];
#pragma unroll
    for (int kk = 0; kk < 4; ++kk) {
        bf16x8 a = *(const bf16x8*)(Abase + kk * 32);
#pragma unroll
        for (int q = 0; q < NT; ++q) {
            bf16x8 b = *(const bf16x8*)(Bbase + q * 16 * LDK + kk * 32);
            acc[q] = __builtin_amdgcn_mfma_f32_16x16x32_bf16(a, b, acc[q], 0, 0, 0);
        }
    }

    const int rb = row0 + wave * 16 + kq * 4;
#pragma unroll
    for (int r = 0; r < 4; ++r) {
        int gr = rb + r;
        if (gr < N) {
            float sc2 = rsqrtf(1.0f + (float)deg[gr]) * oscale;
#pragma unroll
            for (int q = 0; q < NT; q += 2) {
                int pk = __builtin_amdgcn_cvt_pk_fp8_f32(acc[q][r] * sc2,
                                                         acc[q + 1][r] * sc2, 0, false);
                C[(size_t)gr * BN + q * 16 + lrow]       = (unsigned char)(pk & 0xff);
                C[(size_t)gr * BN + (q + 1) * 16 + lrow] = (unsigned char)((pk >> 8) & 0xff);
            }
        }
    }
}

__device__ inline void dec8(uint2 v, f32x2& x0, f32x2& x1, f32x2& x2, f32x2& x3) {
    x0 += __builtin_amdgcn_cvt_pk_f32_fp8((int)v.x, false);
    x1 += __builtin_amdgcn_cvt_pk_f32_fp8((int)v.x, true);
    x2 += __builtin_amdgcn_cvt_pk_f32_fp8((int)v.y, false);
    x3 += __builtin_amdgcn_cvt_pk_f32_fp8((int)v.y, true);
}

__device__ inline void dec16(uint4 v, f32x2& x0, f32x2& x1, f32x2& x2, f32x2& x3,
                             f32x2& x4, f32x2& x5, f32x2& x6, f32x2& x7) {
    x0 += __builtin_amdgcn_cvt_pk_f32_fp8((int)v.x, false);
    x1 += __builtin_amdgcn_cvt_pk_f32_fp8((int)v.x, true);
    x2 += __builtin_amdgcn_cvt_pk_f32_fp8((int)v.y, false);
    x3 += __builtin_amdgcn_cvt_pk_f32_fp8((int)v.y, true);
    x4 += __builtin_amdgcn_cvt_pk_f32_fp8((int)v.z, false);
    x5 += __builtin_amdgcn_cvt_pk_f32_fp8((int)v.z, true);
    x6 += __builtin_amdgcn_cvt_pk_f32_fp8((int)v.w, false);
    x7 += __builtin_amdgcn_cvt_pk_f32_fp8((int)v.w, true);
}

// ---------------- fused gather1 + layer-2 GEMM ----------------
// 512 threads / 64 nodes per block. One 8-lane octet per node (fully parallel);
// lane sl covers 16 fp8 cols (one uint4 per edge). LDS 34.8 KB -> 4 blocks/CU;
// launch_bounds forces VGPR<=64 -> 32 waves/CU.

__global__ __launch_bounds__(512, 8) void fuse2_k(const unsigned char* __restrict__ hs,
                                                  const int* __restrict__ off,
                                                  const int* __restrict__ srcs,
                                                  const int* __restrict__ deg,
                                                  const float* __restrict__ b1,
                                                  const unsigned short* __restrict__ Bt,
                                                  unsigned char* __restrict__ C,
                                                  int N) {
    constexpr int LDK = DIN + 8;
    __shared__ unsigned short As[64 * LDK];
    __shared__ unsigned short Bs[NCLS * LDK];
    const int tid  = threadIdx.x;
    const int row0 = blockIdx.x * 64;

    for (int idx = tid; idx < NCLS * 16; idx += 512) {
        int n = idx >> 4, c = (idx & 15) << 3;
        *(uint4*)&Bs[n * LDK + c] = *(const uint4*)&Bt[n * DIN + c];
    }

    // ---- phase 1: octet-per-node gather/aggregate into As ----
    const int oc = tid >> 3;           // octet 0..63 == As row
    const int sl = tid & 7;            // covers fp8 cols 16*sl .. 16*sl+15
    const int node = row0 + oc;
    const uint4* hp = (const uint4*)hs;  // hs1 row = 8 x uint4

    if (node < N) {
        const int beg = off[node], end = off[node + 1];
        f32x2 a0={0.f,0.f},a1={0.f,0.f},a2={0.f,0.f},a3={0.f,0.f};
        f32x2 a4={0.f,0.f},a5={0.f,0.f},a6={0.f,0.f},a7={0.f,0.f};
        int i = beg;
        for (; i + 3 < end; i += 4) {
            unsigned s0 = (unsigned)srcs[i],     s1 = (unsigned)srcs[i + 1];
            unsigned s2 = (unsigned)srcs[i + 2], s3 = (unsigned)srcs[i + 3];
            uint4 v0 = hp[s0 * 8u + sl];
            uint4 v1 = hp[s1 * 8u + sl];
            uint4 v2 = hp[s2 * 8u + sl];
            uint4 v3 = hp[s3 * 8u + sl];
            dec16(v0, a0,a1,a2,a3,a4,a5,a6,a7);
            dec16(v1, a0,a1,a2,a3,a4,a5,a6,a7);
            dec16(v2, a0,a1,a2,a3,a4,a5,a6,a7);
            dec16(v3, a0,a1,a2,a3,a4,a5,a6,a7);
        }
        for (; i < end; ++i) {
            uint4 v = hp[(unsigned)srcs[i] * 8u + sl];
            dec16(v, a0,a1,a2,a3,a4,a5,a6,a7);
        }
        {   // self-loop
            uint4 v = hp[(unsigned)node * 8u + sl];
            dec16(v, a0,a1,a2,a3,a4,a5,a6,a7);
        }
        const float d = rsqrtf(1.0f + (float)deg[node]) * (1.0f / SCALE1);
        const float4 w0 = ((const float4*)b1)[sl * 4 + 0];
        const float4 w1 = ((const float4*)b1)[sl * 4 + 1];
        const float4 w2 = ((const float4*)b1)[sl * 4 + 2];
        const float4 w3 = ((const float4*)b1)[sl * 4 + 3];
        float o0  = fmaxf(fmaf(d, a0.x, w0.x), 0.f);
        float o1  = fmaxf(fmaf(d, a0.y, w0.y), 0.f);
        float o2  = fmaxf(fmaf(d, a1.x, w0.z), 0.f);
        float o3  = fmaxf(fmaf(d, a1.y, w0.w), 0.f);
        float o4  = fmaxf(fmaf(d, a2.x, w1.x), 0.f);
        float o5  = fmaxf(fmaf(d, a2.y, w1.y), 0.f);
        float o6  = fmaxf(fmaf(d, a3.x, w1.z), 0.f);
        float o7  = fmaxf(fmaf(d, a3.y, w1.w), 0.f);
        float o8  = fmaxf(fmaf(d, a4.x, w2.x), 0.f);
        float o9  = fmaxf(fmaf(d, a4.y, w2.y), 0.f);
        float o10 = fmaxf(fmaf(d, a5.x, w2.z), 0.f);
        float o11 = fmaxf(fmaf(d, a5.y, w2.w), 0.f);
        float o12 = fmaxf(fmaf(d, a6.x, w3.x), 0.f);
        float o13 = fmaxf(fmaf(d, a6.y, w3.y), 0.f);
        float o14 = fmaxf(fmaf(d, a7.x, w3.z), 0.f);
        float o15 = fmaxf(fmaf(d, a7.y, w3.w), 0.f);
        uint4 u0, u1;
        u0.x = (unsigned)f2bf(o0)  | ((unsigned)f2bf(o1)  << 16);
        u0.y = (unsigned)f2bf(o2)  | ((unsigned)f2bf(o3)  << 16);
        u0.z = (unsigned)f2bf(o4)  | ((unsigned)f2bf(o5)  << 16);
        u0.w = (unsigned)f2bf(o6)  | ((unsigned)f2bf(o7)  << 16);
        u1.x = (unsigned)f2bf(o8)  | ((unsigned)f2bf(o9)  << 16);
        u1.y = (unsigned)f2bf(o10) | ((unsigned)f2bf(o11) << 16);
        u1.z = (unsigned)f2bf(o12) | ((unsigned)f2bf(o13) << 16);
        u1.w = (unsigned)f2bf(o14) | ((unsigned)f2bf(o15) << 16);
        *(uint4*)&As[oc * LDK + sl * 16]     = u0;
        *(uint4*)&As[oc * LDK + sl * 16 + 8] = u1;
    } else {
        uint4 z = make_uint4(0, 0, 0, 0);
        *(uint4*)&As[oc * LDK + sl * 16]     = z;
        *(uint4*)&As[oc * LDK + sl * 16 + 8] = z;
    }
    __syncthreads();

    // ---- phase 2: As[64x128] @ Bs^T[128x64] -> fp8 C ----
    const int wave = tid >> 6, lane = tid & 63;
    const int ws = wave & 3;           // row stripe (16 rows)
    const int ch = wave >> 2;          // col half (32 cols)
    const int lrow = lane & 15, kq = lane >> 4;
    f32x4 acc0 = (f32x4){0.f,0.f,0.f,0.f};
    f32x4 acc1 = (f32x4){0.f,0.f,0.f,0.f};

    const unsigned short* Abase = &As[(ws * 16 + lrow) * LDK + kq * 8];
    const unsigned short* Bbase = &Bs[(ch * 32 + lrow) * LDK + kq * 8];
#pragma unroll
    for (int kk = 0; kk < 4; ++kk) {
        bf16x8 a  = *(const bf16x8*)(Abase + kk * 32);
        bf16x8 b0 = *(const bf16x8*)(Bbase + kk * 32);
        bf16x8 b1v= *(const bf16x8*)(Bbase + 16 * LDK + kk * 32);
        acc0 = __builtin_amdgcn_mfma_f32_16x16x32_bf16(a, b0,  acc0, 0, 0, 0);
        acc1 = __builtin_amdgcn_mfma_f32_16x16x32_bf16(a, b1v, acc1, 0, 0, 0);
    }

    const int rb = row0 + ws * 16 + kq * 4;
#pragma unroll
    for (int r = 0; r < 4; ++r) {
        int gr = rb + r;
        if (gr < N) {
            float sc2 = rsqrtf(1.0f + (float)deg[gr]) * SCALE2;
            int pk = __builtin_amdgcn_cvt_pk_fp8_f32(acc0[r] * sc2, acc1[r] * sc2, 0, false);
            C[(size_t)gr * NCLS + ch * 32 + lrow]      = (unsigned char)(pk & 0xff);
            C[(size_t)gr * NCLS + ch * 32 + 16 + lrow] = (unsigned char)((pk >> 8) & 0xff);
        }
    }
}

// ---------------- gather layer 2 + log_softmax (fp8 in) ----------------
// one 8-lane octet owns one node; lane sl covers cols 8*sl..8*sl+7. unroll 8.

__global__ __launch_bounds__(256) void gather2_k(const unsigned char* __restrict__ hs,
                                                 const int* __restrict__ off,
                                                 const int* __restrict__ srcs,
                                                 const int* __restrict__ deg,
                                                 const float* __restrict__ b2,
                                                 float* __restrict__ out, int N) {
    const int lane = threadIdx.x & 63;
    const int wave = threadIdx.x >> 6;
    const int o8 = lane >> 3;          // octet 0..7 -> node within wave
    const int sl = lane & 7;           // covers cols 8*sl..8*sl+7
    const int node = blockIdx.x * 32 + wave * 8 + o8;
    if (node >= N) return;
    const int beg = off[node], end = off[node + 1];
    const uint2* hp = (const uint2*)hs;            // row = 8 x uint2
    f32x2 A0 = {0.f,0.f}, A1 = {0.f,0.f}, A2 = {0.f,0.f}, A3 = {0.f,0.f};
    f32x2 C0 = {0.f,0.f}, C1 = {0.f,0.f}, C2 = {0.f,0.f}, C3 = {0.f,0.f};
    int i = beg;
    for (; i + 7 < end; i += 8) {
        unsigned s0 = (unsigned)srcs[i],     s1 = (unsigned)srcs[i + 1];
        unsigned s2 = (unsigned)srcs[i + 2], s3 = (unsigned)srcs[i + 3];
        unsigned s4 = (unsigned)srcs[i + 4], s5 = (unsigned)srcs[i + 5];
        unsigned s6 = (unsigned)srcs[i + 6], s7 = (unsigned)srcs[i + 7];
        uint2 v0 = hp[s0 * 8u + sl];
        uint2 v1 = hp[s1 * 8u + sl];
        uint2 v2 = hp[s2 * 8u + sl];
        uint2 v3 = hp[s3 * 8u + sl];
        uint2 v4 = hp[s4 * 8u + sl];
        uint2 v5 = hp[s5 * 8u + sl];
        uint2 v6 = hp[s6 * 8u + sl];
        uint2 v7 = hp[s7 * 8u + sl];
        dec8(v0, A0, A1, A2, A3);
        dec8(v1, C0, C1, C2, C3);
        dec8(v2, A0, A1, A2, A3);
        dec8(v3, C0, C1, C2, C3);
        dec8(v4, A0, A1, A2, A3);
        dec8(v5, C0, C1, C2, C3);
        dec8(v6, A0, A1, A2, A3);
        dec8(v7, C0, C1, C2, C3);
    }
    for (; i + 3 < end; i += 4) {
        unsigned s0 = (unsigned)srcs[i],     s1 = (unsigned)srcs[i + 1];
        unsigned s2 = (unsigned)srcs[i + 2], s3 = (unsigned)srcs[i + 3];
        uint2 v0 = hp[s0 * 8u + sl];
        uint2 v1 = hp[s1 * 8u + sl];
        uint2 v2 = hp[s2 * 8u + sl];
        uint2 v3 = hp[s3 * 8u + sl];
        dec8(v0, A0, A1, A2, A3);
        dec8(v1, C0, C1, C2, C3);
        dec8(v2, A0, A1, A2, A3);
        dec8(v3, C0, C1, C2, C3);
    }
    for (; i < end; ++i) {
        uint2 v = hp[(unsigned)srcs[i] * 8u + sl];
        dec8(v, A0, A1, A2, A3);
    }
    {   // self-loop
        uint2 v = hp[(unsigned)node * 8u + sl];
        dec8(v, C0, C1, C2, C3);
    }
    A0 += C0; A1 += C1; A2 += C2; A3 += C3;

    float d = rsqrtf(1.0f + (float)deg[node]) * (1.0f / SCALE2);
    float4 ba = ((const float4*)b2)[sl * 2];
    float4 bb = ((const float4*)b2)[sl * 2 + 1];
    float v0 = fmaf(d, A0.x, ba.x);
    float v1 = fmaf(d, A0.y, ba.y);
    float v2 = fmaf(d, A1.x, ba.z);
    float v3 = fmaf(d, A1.y, ba.w);
    float v4 = fmaf(d, A2.x, bb.x);
    float v5 = fmaf(d, A2.y, bb.y);
    float v6 = fmaf(d, A3.x, bb.z);
    float v7 = fmaf(d, A3.y, bb.w);
    float m = fmaxf(fmaxf(fmaxf(v0, v1), fmaxf(v2, v3)), fmaxf(fmaxf(v4, v5), fmaxf(v6, v7)));
#pragma unroll
    for (int mk = 1; mk <= 4; mk <<= 1) m = fmaxf(m, __shfl_xor(m, mk, 64));
    float s = __expf(v0 - m) + __expf(v1 - m) + __expf(v2 - m) + __expf(v3 - m)
            + __expf(v4 - m) + __expf(v5 - m) + __expf(v6 - m) + __expf(v7 - m);
#pragma unroll
    for (int mk = 1; mk <= 4; mk <<= 1) s += __shfl_xor(s, mk, 64);
    float ls = m + __logf(s);
    float4 oa, ob;
    oa.x = v0 - ls; oa.y = v1 - ls; oa.z = v2 - ls; oa.w = v3 - ls;
    ob.x = v4 - ls; ob.y = v5 - ls; ob.z = v6 - ls; ob.w = v7 - ls;
    ((float4*)out)[(unsigned)node * 16u + sl * 2]     = oa;
    ((float4*)out)[(unsigned)node * 16u + sl * 2 + 1] = ob;
}

// ---------------- launch ----------------

extern "C" void kernel_launch(void* const* d_in, const int* in_sizes, int n_in,
                              void* d_out, int out_size, void* d_ws, size_t ws_size,
                              hipStream_t stream) {
    const float* x  = (const float*)d_in[0];
    const int*   ei = (const int*)d_in[1];
    const float* W1 = (const float*)d_in[2];
    const float* b1 = (const float*)d_in[3];
    const float* W2 = (const float*)d_in[4];
    const float* b2 = (const float*)d_in[5];
    float* out = (float*)d_out;

    const int N  = in_sizes[0] / DIN;
    const int E  = in_sizes[1] / 2;
    const int NB = (N + BSZ - 1) >> BSH;     // 782
    const int NG = (N + 63) / 64;            // 1563 mgemm blocks

    char* p = (char*)d_ws;
    auto alloc = [&](size_t bytes) { void* r = p; p += (bytes + 255) & ~(size_t)255; return r; };
    int*   deg   = (int*)  alloc((size_t)N * 4);
    int*   gcnt  = (int*)  alloc((size_t)NB * 4);
    int*   bbase = (int*)  alloc((size_t)NB * 4);
    int*   off   = (int*)  alloc((size_t)(N + 1) * 4);
    int*   srcs  = (int*)  alloc((size_t)E * 4);
    unsigned int* tmp = (unsigned int*)alloc((size_t)NB * BCAP * 4);
    unsigned short* wt1 = (unsigned short*)alloc(128 * 128 * 2);
    unsigned short* wt2 = (unsigned short*)alloc(64 * 128 * 2);
    unsigned char*  hs1 = (unsigned char*)alloc((size_t)N * DIN);   // fp8
    unsigned char*  hs2 = (unsigned char*)alloc((size_t)N * NCLS);  // fp8

    wprep_k<<<(N + 255) / 256, 256, 0, stream>>>(W1, W2, wt1, wt2, deg, gcnt, N, NB);
    binA_k<<<(E + 4095) / 4096, 256, 0, stream>>>(ei, gcnt, deg, tmp, E, NB);
    scanb_k<<<1, 1024, 0, stream>>>(gcnt, bbase, NB);
    bmix_k<<<NB + NG, 256, 0, stream>>>(tmp, gcnt, bbase, off, srcs, N, E, NB,
                                        x, wt1, deg, hs1, SCALE1);
    fuse2_k<<<(N + 63) / 64, 512, 0, stream>>>(hs1, off, srcs, deg, b1, wt2, hs2, N);
    gather2_k<<<(N + 31) / 32, 256, 0, stream>>>(hs2, off, srcs, deg, b2, out, N);
}

// Round 10
// 260.707 us; speedup vs baseline: 1.5622x; 1.0264x over previous
//
#include <hip/hip_runtime.h>
#include <math.h>

#define DIN 128   // D_IN == D_HID == 128
#define NCLS 64
#define BSH  8    // log2(bucket size): 256 dst-nodes per bucket
#define BSZ  256
#define BCAP 5120 // per-bucket capacity: mean 4096, sd ~64 -> +16 sigma
#define SCALE1 64.0f   // hs1 fp8 scale
#define SCALE2 256.0f  // hs2 fp8 scale

typedef __attribute__((ext_vector_type(4))) float  f32x4;
typedef __attribute__((ext_vector_type(2))) float  f32x2;
typedef __attribute__((ext_vector_type(8))) short  bf16x8;   // MFMA A/B frag (4 VGPRs)

__device__ inline unsigned short f2bf(float f) {             // round-to-nearest-even
    unsigned int u = __float_as_uint(f);
    u += 0x7fff + ((u >> 16) & 1);
    return (unsigned short)(u >> 16);
}

// ---------------- W prep: transpose + cast to bf16; zero deg + gcnt ----------------

__global__ __launch_bounds__(256) void wprep_k(const float* __restrict__ W1,
                                               const float* __restrict__ W2,
                                               unsigned short* __restrict__ wt1,
                                               unsigned short* __restrict__ wt2,
                                               int* __restrict__ deg,
                                               int* __restrict__ gcnt, int N, int NB) {
    int i = blockIdx.x * 256 + threadIdx.x;
    if (i < 128 * 128) { int k = i >> 7, n = i & 127; wt1[n * 128 + k] = f2bf(W1[i]); }
    if (i < 128 * 64)  { int k = i >> 6, n = i & 63;  wt2[n * 128 + k] = f2bf(W2[i]); }
    if (i < N)         deg[i] = 0;
    if (i < NB)        gcnt[i] = 0;
}

// ---------------- CSR build phase A: bucket counting sort + per-node degree ----------------
// 1024 threads x 4 edges = 4096 edges/block (391 blocks). 16 waves/block hides the
// LDS-atomic + global-deg-atomic latency that starved the 256-thread version (r9: 14%
// occupancy, 78us). tmp write locality unchanged (~10.5 edges/bucket/block @ BSZ=256).

__global__ __launch_bounds__(1024) void binA_k(const int* __restrict__ ei,
                                               int* __restrict__ gcnt,
                                               int* __restrict__ deg,
                                               unsigned int* __restrict__ tmp,
                                               int E, int NB) {
    __shared__ int lcnt[512];
    __shared__ int gpos[512];
    const int t = threadIdx.x;
    for (int i = t; i < NB; i += 1024) lcnt[i] = 0;
    __syncthreads();

    const int base = blockIdx.x * 4096;
    unsigned int pk[4];
    short bk[4], rk[4];
#pragma unroll
    for (int k = 0; k < 4; ++k) {
        int e = base + k * 1024 + t;
        if (e < E) {
            int s = ei[e];
            int d = ei[E + e];
            atomicAdd(&deg[d], 1);
            int b = d >> BSH;
            pk[k] = ((unsigned int)s << BSH) | (unsigned int)(d & (BSZ - 1));
            bk[k] = (short)b;
            rk[k] = (short)atomicAdd(&lcnt[b], 1);
        } else {
            bk[k] = -1;
        }
    }
    __syncthreads();
    for (int i = t; i < NB; i += 1024)
        gpos[i] = lcnt[i] ? atomicAdd(&gcnt[i], lcnt[i]) : 0;
    __syncthreads();
#pragma unroll
    for (int k = 0; k < 4; ++k) {
        if (bk[k] >= 0) {
            int b = bk[k];
            int pos = gpos[b] + rk[k];
            if (pos < BCAP) tmp[(size_t)b * BCAP + pos] = pk[k];
        }
    }
}

__global__ __launch_bounds__(512) void scanb_k(const int* __restrict__ gcnt,
                                               int* __restrict__ bbase, int NB) {
    __shared__ int tmp[512];
    int t = threadIdx.x;
    int v = (t < NB) ? gcnt[t] : 0;
    tmp[t] = v; __syncthreads();
    for (int o = 1; o < 512; o <<= 1) {
        int x = (t >= o) ? tmp[t - o] : 0;
        __syncthreads();
        tmp[t] += x;
        __syncthreads();
    }
    if (t < NB) bbase[t] = (t == 0) ? 0 : tmp[t - 1];
}

// ---------------- bmix: binB (blocks < NB) || layer-1 MFMA GEMM ----------------
// binB: per-bucket counting sort by dst&255 -> CSR srcs + off. Writes stay within the
// bucket's contiguous ~16KB segment (no write amplification — the round-8 lesson).
// mgemm: BM=64, BN=128, fp32 A -> bf16 LDS -> MFMA -> fp8, rsqrt(1+deg) inline.
// LDS overlaid in one 52224B array so mgemm keeps 3 blocks/CU (binB uses 24.6KB).

__global__ __launch_bounds__(256) void bmix_k(const unsigned int* __restrict__ tmp,
                                              const int* __restrict__ gcnt,
                                              const int* __restrict__ bbase,
                                              int* __restrict__ off,
                                              int* __restrict__ srcs,
                                              int N, int E, int NB,
                                              const float* __restrict__ A,
                                              const unsigned short* __restrict__ Bt,
                                              const int* __restrict__ deg,
                                              unsigned char* __restrict__ C,
                                              float oscale) {
    constexpr int LDK = DIN + 8;
    constexpr int BN  = 128;
    __shared__ __align__(16) unsigned char raw[64 * LDK * 2 + BN * LDK * 2]; // 52224 B
    const int t = threadIdx.x;

    if ((int)blockIdx.x < NB) {
        // ---- binB path (24.6 KB of raw) ----
        unsigned int* stg  = (unsigned int*)raw;               // BCAP u32 = 20480 B
        int* lcnt = (int*)(raw + BCAP * 4);                    // 256 ints each
        int* sc   = lcnt + BSZ;
        int* loff = sc + BSZ;
        int* lcur = loff + BSZ;
        const int b = blockIdx.x;
        int cnt = gcnt[b];
        if (cnt > BCAP) cnt = BCAP;
        const int base = bbase[b];
        lcnt[t] = 0; lcur[t] = 0;
        __syncthreads();
        for (int i = t; i < cnt; i += 256) {
            unsigned int v = tmp[(size_t)b * BCAP + i];
            stg[i] = v;
            atomicAdd(&lcnt[v & (BSZ - 1u)], 1);
        }
        __syncthreads();
        sc[t] = lcnt[t];
        __syncthreads();
        for (int o = 1; o < BSZ; o <<= 1) {
            int x = (t >= o) ? sc[t - o] : 0;
            __syncthreads();
            sc[t] += x;
            __syncthreads();
        }
        int excl = (t == 0) ? 0 : sc[t - 1];
        loff[t] = excl;
        int node = b * BSZ + t;
        if (node <= N) off[node] = base + excl;
        __syncthreads();
        for (int i = t; i < cnt; i += 256) {
            unsigned int v = stg[i];
            int l = v & (BSZ - 1u);
            int r = atomicAdd(&lcur[l], 1);
            srcs[base + loff[l] + r] = (int)(v >> BSH);
        }
        return;
    }

    // ---- mgemm path ----
    unsigned short* As = (unsigned short*)raw;                 // 64 x LDK
    unsigned short* Bs = As + 64 * LDK;                        // BN x LDK
    const int row0 = ((int)blockIdx.x - NB) * 64;

    for (int idx = t; idx < BN * 16; idx += 256) {
        int n = idx >> 4, c = (idx & 15) << 3;
        *(uint4*)&Bs[n * LDK + c] = *(const uint4*)&Bt[n * DIN + c];
    }
    for (int idx = t; idx < 64 * 16; idx += 256) {
        int r = idx >> 4, c = (idx & 15) << 3;
        int gr = row0 + r;
        unsigned short v[8];
        if (gr < N) {
            f32x4 a0 = *(const f32x4*)&A[(size_t)gr * DIN + c];
            f32x4 a1 = *(const f32x4*)&A[(size_t)gr * DIN + c + 4];
            v[0] = f2bf(a0.x); v[1] = f2bf(a0.y); v[2] = f2bf(a0.z); v[3] = f2bf(a0.w);
            v[4] = f2bf(a1.x); v[5] = f2bf(a1.y); v[6] = f2bf(a1.z); v[7] = f2bf(a1.w);
        } else {
#pragma unroll
            for (int j = 0; j < 8; ++j) v[j] = 0;
        }
        *(uint4*)&As[r * LDK + c] = *(const uint4*)v;
    }
    __syncthreads();

    const int wave = t >> 6, lane = t & 63;
    const int lrow = lane & 15, kq = lane >> 4;
    constexpr int NT = BN / 16;
    f32x4 acc[NT];
#pragma unroll
    for (int q = 0; q < NT; ++q) acc[q] = (f32x4){0.f, 0.f, 0.f, 0.f};

    const unsigned short* Abase = &As[(wave * 16 + lrow) * LDK + kq * 8];
    const unsigned short* Bbase = &Bs[lrow * LDK + kq * 8];
#pragma unroll
    for (int kk = 0; kk < 4; ++kk) {
        bf16x8 a = *(const bf16x8*)(Abase + kk * 32);
#pragma unroll
        for (int q = 0; q < NT; ++q) {
            bf16x8 b = *(const bf16x8*)(Bbase + q * 16 * LDK + kk * 32);
            acc[q] = __builtin_amdgcn_mfma_f32_16x16x32_bf16(a, b, acc[q], 0, 0, 0);
        }
    }

    const int rb = row0 + wave * 16 + kq * 4;
#pragma unroll
    for (int r = 0; r < 4; ++r) {
        int gr = rb + r;
        if (gr < N) {
            float sc2 = rsqrtf(1.0f + (float)deg[gr]) * oscale;
#pragma unroll
            for (int q = 0; q < NT; q += 2) {
                int pk = __builtin_amdgcn_cvt_pk_fp8_f32(acc[q][r] * sc2,
                                                         acc[q + 1][r] * sc2, 0, false);
                C[(size_t)gr * BN + q * 16 + lrow]       = (unsigned char)(pk & 0xff);
                C[(size_t)gr * BN + (q + 1) * 16 + lrow] = (unsigned char)((pk >> 8) & 0xff);
            }
        }
    }
}

__device__ inline void dec8(uint2 v, f32x2& x0, f32x2& x1, f32x2& x2, f32x2& x3) {
    x0 += __builtin_amdgcn_cvt_pk_f32_fp8((int)v.x, false);
    x1 += __builtin_amdgcn_cvt_pk_f32_fp8((int)v.x, true);
    x2 += __builtin_amdgcn_cvt_pk_f32_fp8((int)v.y, false);
    x3 += __builtin_amdgcn_cvt_pk_f32_fp8((int)v.y, true);
}

__device__ inline void dec16(uint4 v, f32x2& x0, f32x2& x1, f32x2& x2, f32x2& x3,
                             f32x2& x4, f32x2& x5, f32x2& x6, f32x2& x7) {
    x0 += __builtin_amdgcn_cvt_pk_f32_fp8((int)v.x, false);
    x1 += __builtin_amdgcn_cvt_pk_f32_fp8((int)v.x, true);
    x2 += __builtin_amdgcn_cvt_pk_f32_fp8((int)v.y, false);
    x3 += __builtin_amdgcn_cvt_pk_f32_fp8((int)v.y, true);
    x4 += __builtin_amdgcn_cvt_pk_f32_fp8((int)v.z, false);
    x5 += __builtin_amdgcn_cvt_pk_f32_fp8((int)v.z, true);
    x6 += __builtin_amdgcn_cvt_pk_f32_fp8((int)v.w, false);
    x7 += __builtin_amdgcn_cvt_pk_f32_fp8((int)v.w, true);
}

// ---------------- fused gather1 + layer-2 GEMM ----------------
// 512 threads / 64 nodes per block. One 8-lane octet per node (fully parallel);
// lane sl covers 16 fp8 cols (one uint4 per edge). LDS 34.8 KB -> 4 blocks/CU;
// launch_bounds forces VGPR<=64 -> 32 waves/CU.

__global__ __launch_bounds__(512, 8) void fuse2_k(const unsigned char* __restrict__ hs,
                                                  const int* __restrict__ off,
                                                  const int* __restrict__ srcs,
                                                  const int* __restrict__ deg,
                                                  const float* __restrict__ b1,
                                                  const unsigned short* __restrict__ Bt,
                                                  unsigned char* __restrict__ C,
                                                  int N) {
    constexpr int LDK = DIN + 8;
    __shared__ unsigned short As[64 * LDK];
    __shared__ unsigned short Bs[NCLS * LDK];
    const int tid  = threadIdx.x;
    const int row0 = blockIdx.x * 64;

    for (int idx = tid; idx < NCLS * 16; idx += 512) {
        int n = idx >> 4, c = (idx & 15) << 3;
        *(uint4*)&Bs[n * LDK + c] = *(const uint4*)&Bt[n * DIN + c];
    }

    // ---- phase 1: octet-per-node gather/aggregate into As ----
    const int oc = tid >> 3;           // octet 0..63 == As row
    const int sl = tid & 7;            // covers fp8 cols 16*sl .. 16*sl+15
    const int node = row0 + oc;
    const uint4* hp = (const uint4*)hs;  // hs1 row = 8 x uint4

    if (node < N) {
        const int beg = off[node], end = off[node + 1];
        f32x2 a0={0.f,0.f},a1={0.f,0.f},a2={0.f,0.f},a3={0.f,0.f};
        f32x2 a4={0.f,0.f},a5={0.f,0.f},a6={0.f,0.f},a7={0.f,0.f};
        int i = beg;
        for (; i + 3 < end; i += 4) {
            unsigned s0 = (unsigned)srcs[i],     s1 = (unsigned)srcs[i + 1];
            unsigned s2 = (unsigned)srcs[i + 2], s3 = (unsigned)srcs[i + 3];
            uint4 v0 = hp[s0 * 8u + sl];
            uint4 v1 = hp[s1 * 8u + sl];
            uint4 v2 = hp[s2 * 8u + sl];
            uint4 v3 = hp[s3 * 8u + sl];
            dec16(v0, a0,a1,a2,a3,a4,a5,a6,a7);
            dec16(v1, a0,a1,a2,a3,a4,a5,a6,a7);
            dec16(v2, a0,a1,a2,a3,a4,a5,a6,a7);
            dec16(v3, a0,a1,a2,a3,a4,a5,a6,a7);
        }
        for (; i < end; ++i) {
            uint4 v = hp[(unsigned)srcs[i] * 8u + sl];
            dec16(v, a0,a1,a2,a3,a4,a5,a6,a7);
        }
        {   // self-loop
            uint4 v = hp[(unsigned)node * 8u + sl];
            dec16(v, a0,a1,a2,a3,a4,a5,a6,a7);
        }
        const float d = rsqrtf(1.0f + (float)deg[node]) * (1.0f / SCALE1);
        const float4 w0 = ((const float4*)b1)[sl * 4 + 0];
        const float4 w1 = ((const float4*)b1)[sl * 4 + 1];
        const float4 w2 = ((const float4*)b1)[sl * 4 + 2];
        const float4 w3 = ((const float4*)b1)[sl * 4 + 3];
        float o0  = fmaxf(fmaf(d, a0.x, w0.x), 0.f);
        float o1  = fmaxf(fmaf(d, a0.y, w0.y), 0.f);
        float o2  = fmaxf(fmaf(d, a1.x, w0.z), 0.f);
        float o3  = fmaxf(fmaf(d, a1.y, w0.w), 0.f);
        float o4  = fmaxf(fmaf(d, a2.x, w1.x), 0.f);
        float o5  = fmaxf(fmaf(d, a2.y, w1.y), 0.f);
        float o6  = fmaxf(fmaf(d, a3.x, w1.z), 0.f);
        float o7  = fmaxf(fmaf(d, a3.y, w1.w), 0.f);
        float o8  = fmaxf(fmaf(d, a4.x, w2.x), 0.f);
        float o9  = fmaxf(fmaf(d, a4.y, w2.y), 0.f);
        float o10 = fmaxf(fmaf(d, a5.x, w2.z), 0.f);
        float o11 = fmaxf(fmaf(d, a5.y, w2.w), 0.f);
        float o12 = fmaxf(fmaf(d, a6.x, w3.x), 0.f);
        float o13 = fmaxf(fmaf(d, a6.y, w3.y), 0.f);
        float o14 = fmaxf(fmaf(d, a7.x, w3.z), 0.f);
        float o15 = fmaxf(fmaf(d, a7.y, w3.w), 0.f);
        uint4 u0, u1;
        u0.x = (unsigned)f2bf(o0)  | ((unsigned)f2bf(o1)  << 16);
        u0.y = (unsigned)f2bf(o2)  | ((unsigned)f2bf(o3)  << 16);
        u0.z = (unsigned)f2bf(o4)  | ((unsigned)f2bf(o5)  << 16);
        u0.w = (unsigned)f2bf(o6)  | ((unsigned)f2bf(o7)  << 16);
        u1.x = (unsigned)f2bf(o8)  | ((unsigned)f2bf(o9)  << 16);
        u1.y = (unsigned)f2bf(o10) | ((unsigned)f2bf(o11) << 16);
        u1.z = (unsigned)f2bf(o12) | ((unsigned)f2bf(o13) << 16);
        u1.w = (unsigned)f2bf(o14) | ((unsigned)f2bf(o15) << 16);
        *(uint4*)&As[oc * LDK + sl * 16]     = u0;
        *(uint4*)&As[oc * LDK + sl * 16 + 8] = u1;
    } else {
        uint4 z = make_uint4(0, 0, 0, 0);
        *(uint4*)&As[oc * LDK + sl * 16]     = z;
        *(uint4*)&As[oc * LDK + sl * 16 + 8] = z;
    }
    __syncthreads();

    // ---- phase 2: As[64x128] @ Bs^T[128x64] -> fp8 C ----
    const int wave = tid >> 6, lane = tid & 63;
    const int ws = wave & 3;           // row stripe (16 rows)
    const int ch = wave >> 2;          // col half (32 cols)
    const int lrow = lane & 15, kq = lane >> 4;
    f32x4 acc0 = (f32x4){0.f,0.f,0.f,0.f};
    f32x4 acc1 = (f32x4){0.f,0.f,0.f,0.f};

    const unsigned short* Abase = &As[(ws * 16 + lrow) * LDK + kq * 8];
    const unsigned short* Bbase = &Bs[(ch * 32 + lrow) * LDK + kq * 8];
#pragma unroll
    for (int kk = 0; kk < 4; ++kk) {
        bf16x8 a  = *(const bf16x8*)(Abase + kk * 32);
        bf16x8 b0 = *(const bf16x8*)(Bbase + kk * 32);
        bf16x8 b1v= *(const bf16x8*)(Bbase + 16 * LDK + kk * 32);
        acc0 = __builtin_amdgcn_mfma_f32_16x16x32_bf16(a, b0,  acc0, 0, 0, 0);
        acc1 = __builtin_amdgcn_mfma_f32_16x16x32_bf16(a, b1v, acc1, 0, 0, 0);
    }

    const int rb = row0 + ws * 16 + kq * 4;
#pragma unroll
    for (int r = 0; r < 4; ++r) {
        int gr = rb + r;
        if (gr < N) {
            float sc2 = rsqrtf(1.0f + (float)deg[gr]) * SCALE2;
            int pk = __builtin_amdgcn_cvt_pk_fp8_f32(acc0[r] * sc2, acc1[r] * sc2, 0, false);
            C[(size_t)gr * NCLS + ch * 32 + lrow]      = (unsigned char)(pk & 0xff);
            C[(size_t)gr * NCLS + ch * 32 + 16 + lrow] = (unsigned char)((pk >> 8) & 0xff);
        }
    }
}

// ---------------- gather layer 2 + log_softmax (fp8 in) ----------------
// one 8-lane octet owns one node; lane sl covers cols 8*sl..8*sl+7. unroll 8.

__global__ __launch_bounds__(256) void gather2_k(const unsigned char* __restrict__ hs,
                                                 const int* __restrict__ off,
                                                 const int* __restrict__ srcs,
                                                 const int* __restrict__ deg,
                                                 const float* __restrict__ b2,
                                                 float* __restrict__ out, int N) {
    const int lane = threadIdx.x & 63;
    const int wave = threadIdx.x >> 6;
    const int o8 = lane >> 3;          // octet 0..7 -> node within wave
    const int sl = lane & 7;           // covers cols 8*sl..8*sl+7
    const int node = blockIdx.x * 32 + wave * 8 + o8;
    if (node >= N) return;
    const int beg = off[node], end = off[node + 1];
    const uint2* hp = (const uint2*)hs;            // row = 8 x uint2
    f32x2 A0 = {0.f,0.f}, A1 = {0.f,0.f}, A2 = {0.f,0.f}, A3 = {0.f,0.f};
    f32x2 C0 = {0.f,0.f}, C1 = {0.f,0.f}, C2 = {0.f,0.f}, C3 = {0.f,0.f};
    int i = beg;
    for (; i + 7 < end; i += 8) {
        unsigned s0 = (unsigned)srcs[i],     s1 = (unsigned)srcs[i + 1];
        unsigned s2 = (unsigned)srcs[i + 2], s3 = (unsigned)srcs[i + 3];
        unsigned s4 = (unsigned)srcs[i + 4], s5 = (unsigned)srcs[i + 5];
        unsigned s6 = (unsigned)srcs[i + 6], s7 = (unsigned)srcs[i + 7];
        uint2 v0 = hp[s0 * 8u + sl];
        uint2 v1 = hp[s1 * 8u + sl];
        uint2 v2 = hp[s2 * 8u + sl];
        uint2 v3 = hp[s3 * 8u + sl];
        uint2 v4 = hp[s4 * 8u + sl];
        uint2 v5 = hp[s5 * 8u + sl];
        uint2 v6 = hp[s6 * 8u + sl];
        uint2 v7 = hp[s7 * 8u + sl];
        dec8(v0, A0, A1, A2, A3);
        dec8(v1, C0, C1, C2, C3);
        dec8(v2, A0, A1, A2, A3);
        dec8(v3, C0, C1, C2, C3);
        dec8(v4, A0, A1, A2, A3);
        dec8(v5, C0, C1, C2, C3);
        dec8(v6, A0, A1, A2, A3);
        dec8(v7, C0, C1, C2, C3);
    }
    for (; i + 3 < end; i += 4) {
        unsigned s0 = (unsigned)srcs[i],     s1 = (unsigned)srcs[i + 1];
        unsigned s2 = (unsigned)srcs[i + 2], s3 = (unsigned)srcs[i + 3];
        uint2 v0 = hp[s0 * 8u + sl];
        uint2 v1 = hp[s1 * 8u + sl];
        uint2 v2 = hp[s2 * 8u + sl];
        uint2 v3 = hp[s3 * 8u + sl];
        dec8(v0, A0, A1, A2, A3);
        dec8(v1, C0, C1, C2, C3);
        dec8(v2, A0, A1, A2, A3);
        dec8(v3, C0, C1, C2, C3);
    }
    for (; i < end; ++i) {
        uint2 v = hp[(unsigned)srcs[i] * 8u + sl];
        dec8(v, A0, A1, A2, A3);
    }
    {   // self-loop
        uint2 v = hp[(unsigned)node * 8u + sl];
        dec8(v, C0, C1, C2, C3);
    }
    A0 += C0; A1 += C1; A2 += C2; A3 += C3;

    float d = rsqrtf(1.0f + (float)deg[node]) * (1.0f / SCALE2);
    float4 ba = ((const float4*)b2)[sl * 2];
    float4 bb = ((const float4*)b2)[sl * 2 + 1];
    float v0 = fmaf(d, A0.x, ba.x);
    float v1 = fmaf(d, A0.y, ba.y);
    float v2 = fmaf(d, A1.x, ba.z);
    float v3 = fmaf(d, A1.y, ba.w);
    float v4 = fmaf(d, A2.x, bb.x);
    float v5 = fmaf(d, A2.y, bb.y);
    float v6 = fmaf(d, A3.x, bb.z);
    float v7 = fmaf(d, A3.y, bb.w);
    float m = fmaxf(fmaxf(fmaxf(v0, v1), fmaxf(v2, v3)), fmaxf(fmaxf(v4, v5), fmaxf(v6, v7)));
#pragma unroll
    for (int mk = 1; mk <= 4; mk <<= 1) m = fmaxf(m, __shfl_xor(m, mk, 64));
    float s = __expf(v0 - m) + __expf(v1 - m) + __expf(v2 - m) + __expf(v3 - m)
            + __expf(v4 - m) + __expf(v5 - m) + __expf(v6 - m) + __expf(v7 - m);
#pragma unroll
    for (int mk = 1; mk <= 4; mk <<= 1) s += __shfl_xor(s, mk, 64);
    float ls = m + __logf(s);
    float4 oa, ob;
    oa.x = v0 - ls; oa.y = v1 - ls; oa.z = v2 - ls; oa.w = v3 - ls;
    ob.x = v4 - ls; ob.y = v5 - ls; ob.z = v6 - ls; ob.w = v7 - ls;
    ((float4*)out)[(unsigned)node * 16u + sl * 2]     = oa;
    ((float4*)out)[(unsigned)node * 16u + sl * 2 + 1] = ob;
}

// ---------------- launch ----------------

extern "C" void kernel_launch(void* const* d_in, const int* in_sizes, int n_in,
                              void* d_out, int out_size, void* d_ws, size_t ws_size,
                              hipStream_t stream) {
    const float* x  = (const float*)d_in[0];
    const int*   ei = (const int*)d_in[1];
    const float* W1 = (const float*)d_in[2];
    const float* b1 = (const float*)d_in[3];
    const float* W2 = (const float*)d_in[4];
    const float* b2 = (const float*)d_in[5];
    float* out = (float*)d_out;

    const int N  = in_sizes[0] / DIN;
    const int E  = in_sizes[1] / 2;
    const int NB = (N + BSZ - 1) >> BSH;     // 391
    const int NG = (N + 63) / 64;            // 1563 mgemm blocks

    char* p = (char*)d_ws;
    auto alloc = [&](size_t bytes) { void* r = p; p += (bytes + 255) & ~(size_t)255; return r; };
    int*   deg   = (int*)  alloc((size_t)N * 4);
    int*   gcnt  = (int*)  alloc((size_t)NB * 4);
    int*   bbase = (int*)  alloc((size_t)NB * 4);
    int*   off   = (int*)  alloc((size_t)(N + 1) * 4);
    int*   srcs  = (int*)  alloc((size_t)E * 4);
    unsigned int* tmp = (unsigned int*)alloc((size_t)NB * BCAP * 4);
    unsigned short* wt1 = (unsigned short*)alloc(128 * 128 * 2);
    unsigned short* wt2 = (unsigned short*)alloc(64 * 128 * 2);
    unsigned char*  hs1 = (unsigned char*)alloc((size_t)N * DIN);   // fp8
    unsigned char*  hs2 = (unsigned char*)alloc((size_t)N * NCLS);  // fp8

    wprep_k<<<(N + 255) / 256, 256, 0, stream>>>(W1, W2, wt1, wt2, deg, gcnt, N, NB);
    binA_k<<<(E + 4095) / 4096, 1024, 0, stream>>>(ei, gcnt, deg, tmp, E, NB);
    scanb_k<<<1, 512, 0, stream>>>(gcnt, bbase, NB);
    bmix_k<<<NB + NG, 256, 0, stream>>>(tmp, gcnt, bbase, off, srcs, N, E, NB,
                                        x, wt1, deg, hs1, SCALE1);
    fuse2_k<<<(N + 63) / 64, 512, 0, stream>>>(hs1, off, srcs, deg, b1, wt2, hs2, N);
    gather2_k<<<(N + 31) / 32, 256, 0, stream>>>(hs2, off, srcs, deg, b2, out, N);
}

// Round 11
// 202.622 us; speedup vs baseline: 2.0100x; 1.2867x over previous
//
#include <hip/hip_runtime.h>
#include <math.h>

#define DIN 128   // D_IN == D_HID == 128
#define NCLS 64
#define BSH  8    // log2(bucket size): 256 dst-nodes per bucket
#define BSZ  256
#define BCAP 5120 // per-bucket capacity: mean 4096, sd ~64 -> +16 sigma
#define SCALE1 64.0f   // hs1 fp8 scale
#define SCALE2 256.0f  // hs2 fp8 scale

typedef __attribute__((ext_vector_type(4))) float  f32x4;
typedef __attribute__((ext_vector_type(2))) float  f32x2;
typedef __attribute__((ext_vector_type(8))) short  bf16x8;   // MFMA A/B frag (4 VGPRs)

__device__ inline unsigned short f2bf(float f) {             // round-to-nearest-even
    unsigned int u = __float_as_uint(f);
    u += 0x7fff + ((u >> 16) & 1);
    return (unsigned short)(u >> 16);
}

// ---------------- W prep: transpose + cast to bf16; zero gcnt ----------------

__global__ __launch_bounds__(256) void wprep_k(const float* __restrict__ W1,
                                               const float* __restrict__ W2,
                                               unsigned short* __restrict__ wt1,
                                               unsigned short* __restrict__ wt2,
                                               int* __restrict__ gcnt, int NB) {
    int i = blockIdx.x * 256 + threadIdx.x;
    if (i < 128 * 128) { int k = i >> 7, n = i & 127; wt1[n * 128 + k] = f2bf(W1[i]); }
    if (i < 128 * 64)  { int k = i >> 6, n = i & 63;  wt2[n * 128 + k] = f2bf(W2[i]); }
    if (i < NB)        gcnt[i] = 0;
}

// ---------------- CSR build phase A: bucket sort with COALESCED tmp writes ----------------
// r10 lesson: scattered 4B stores -> 9x write amplification (59.6MB), 76us, occupancy-
// independent. Fix: block-sort edges in LDS by bucket, record each edge's global slot
// (consecutive within a bucket run), then write in sorted order -> coalesced bursts.
// deg atomics removed entirely (dinv now comes from binB's exact counts).

__global__ __launch_bounds__(1024) void binA_k(const int* __restrict__ ei,
                                               int* __restrict__ gcnt,
                                               unsigned int* __restrict__ tmp,
                                               int E, int NB) {
    __shared__ unsigned int spk[4096];   // packed edges, sorted by bucket
    __shared__ unsigned int sgp[4096];   // global tmp index per sorted edge
    __shared__ int lcnt[512], sbase[512], gpos[512];
    const int t = threadIdx.x;
    for (int i = t; i < 512; i += 1024) lcnt[i] = 0;
    __syncthreads();

    const int base = blockIdx.x * 4096;
    unsigned int pk[4];
    short bk[4], rk[4];
#pragma unroll
    for (int k = 0; k < 4; ++k) {
        int e = base + k * 1024 + t;
        if (e < E) {
            int s = ei[e];
            int d = ei[E + e];
            int b = d >> BSH;
            pk[k] = ((unsigned int)s << BSH) | (unsigned int)(d & (BSZ - 1));
            bk[k] = (short)b;
            rk[k] = (short)atomicAdd(&lcnt[b], 1);
        } else {
            bk[k] = -1;
        }
    }
    __syncthreads();
    if (t < 512) sbase[t] = lcnt[t];
    __syncthreads();
    for (int o = 1; o < 512; o <<= 1) {           // inclusive scan over 512 buckets
        int x = 0;
        if (t < 512 && t >= o) x = sbase[t - o];
        __syncthreads();
        if (t < 512) sbase[t] += x;
        __syncthreads();
    }
    if (t < NB) gpos[t] = lcnt[t] ? atomicAdd(&gcnt[t], lcnt[t]) : 0;
    __syncthreads();
#pragma unroll
    for (int k = 0; k < 4; ++k) {
        if (bk[k] >= 0) {
            int b = bk[k];
            int j = sbase[b] - lcnt[b] + rk[k];   // block-local sorted slot
            int p = gpos[b] + rk[k];              // slot within bucket's global region
            spk[j] = pk[k];
            sgp[j] = (p < BCAP) ? ((unsigned int)b * BCAP + (unsigned int)p) : 0xFFFFFFFFu;
        }
    }
    __syncthreads();
    const int cnt = min(4096, E - base);
    for (int j = t; j < cnt; j += 1024) {         // sorted order -> coalesced bursts
        unsigned int g = sgp[j];
        if (g != 0xFFFFFFFFu) tmp[g] = spk[j];
    }
}

__global__ __launch_bounds__(512) void scanb_k(const int* __restrict__ gcnt,
                                               int* __restrict__ bbase, int NB) {
    __shared__ int tmp[512];
    int t = threadIdx.x;
    int v = (t < NB) ? gcnt[t] : 0;
    tmp[t] = v; __syncthreads();
    for (int o = 1; o < 512; o <<= 1) {
        int x = (t >= o) ? tmp[t - o] : 0;
        __syncthreads();
        tmp[t] += x;
        __syncthreads();
    }
    if (t < NB) bbase[t] = (t == 0) ? 0 : tmp[t - 1];
}

// ---------------- bmix: binB (blocks < NB) || layer-1 MFMA GEMM ----------------
// binB: per-bucket counting sort by dst&255 -> CSR srcs + off + dinv (exact counts).
// mgemm: BM=64, BN=128, fp32 A -> bf16 LDS -> MFMA -> fp8 UNSCALED (dinv applied
// per-edge in fuse2), so mgemm has no dependency on degree data.

__global__ __launch_bounds__(256) void bmix_k(const unsigned int* __restrict__ tmp,
                                              const int* __restrict__ gcnt,
                                              const int* __restrict__ bbase,
                                              int* __restrict__ off,
                                              float* __restrict__ dinv,
                                              int* __restrict__ srcs,
                                              int N, int E, int NB,
                                              const float* __restrict__ A,
                                              const unsigned short* __restrict__ Bt,
                                              unsigned char* __restrict__ C,
                                              float oscale) {
    constexpr int LDK = DIN + 8;
    constexpr int BN  = 128;
    __shared__ __align__(16) unsigned char raw[64 * LDK * 2 + BN * LDK * 2]; // 52224 B
    const int t = threadIdx.x;

    if ((int)blockIdx.x < NB) {
        // ---- binB path (24.6 KB of raw) ----
        unsigned int* stg  = (unsigned int*)raw;               // BCAP u32 = 20480 B
        int* lcnt = (int*)(raw + BCAP * 4);                    // 256 ints each
        int* sc   = lcnt + BSZ;
        int* loff = sc + BSZ;
        int* lcur = loff + BSZ;
        const int b = blockIdx.x;
        int cnt = gcnt[b];
        if (cnt > BCAP) cnt = BCAP;
        const int base = bbase[b];
        lcnt[t] = 0; lcur[t] = 0;
        __syncthreads();
        for (int i = t; i < cnt; i += 256) {
            unsigned int v = tmp[(size_t)b * BCAP + i];
            stg[i] = v;
            atomicAdd(&lcnt[v & (BSZ - 1u)], 1);
        }
        __syncthreads();
        sc[t] = lcnt[t];
        __syncthreads();
        for (int o = 1; o < BSZ; o <<= 1) {
            int x = (t >= o) ? sc[t - o] : 0;
            __syncthreads();
            sc[t] += x;
            __syncthreads();
        }
        int excl = (t == 0) ? 0 : sc[t - 1];
        loff[t] = excl;
        int node = b * BSZ + t;
        if (node <= N) off[node] = base + excl;
        if (node < N)  dinv[node] = rsqrtf(1.0f + (float)lcnt[t]);
        __syncthreads();
        for (int i = t; i < cnt; i += 256) {
            unsigned int v = stg[i];
            int l = v & (BSZ - 1u);
            int r = atomicAdd(&lcur[l], 1);
            srcs[base + loff[l] + r] = (int)(v >> BSH);
        }
        return;
    }

    // ---- mgemm path: hs1 = fp8(oscale * (x@W1)), no per-row scale ----
    unsigned short* As = (unsigned short*)raw;                 // 64 x LDK
    unsigned short* Bs = As + 64 * LDK;                        // BN x LDK
    const int row0 = ((int)blockIdx.x - NB) * 64;

    for (int idx = t; idx < BN * 16; idx += 256) {
        int n = idx >> 4, c = (idx & 15) << 3;
        *(uint4*)&Bs[n * LDK + c] = *(const uint4*)&Bt[n * DIN + c];
    }
    for (int idx = t; idx < 64 * 16; idx += 256) {
        int r = idx >> 4, c = (idx & 15) << 3;
        int gr = row0 + r;
        unsigned short v[8];
        if (gr < N) {
            f32x4 a0 = *(const f32x4*)&A[(size_t)gr * DIN + c];
            f32x4 a1 = *(const f32x4*)&A[(size_t)gr * DIN + c + 4];
            v[0] = f2bf(a0.x); v[1] = f2bf(a0.y); v[2] = f2bf(a0.z); v[3] = f2bf(a0.w);
            v[4] = f2bf(a1.x); v[5] = f2bf(a1.y); v[6] = f2bf(a1.z); v[7] = f2bf(a1.w);
        } else {
#pragma unroll
            for (int j = 0; j < 8; ++j) v[j] = 0;
        }
        *(uint4*)&As[r * LDK + c] = *(const uint4*)v;
    }
    __syncthreads();

    const int wave = t >> 6, lane = t & 63;
    const int lrow = lane & 15, kq = lane >> 4;
    constexpr int NT = BN / 16;
    f32x4 acc[NT];
#pragma unroll
    for (int q = 0; q < NT; ++q) acc[q] = (f32x4){0.f, 0.f, 0.f, 0.f};

    const unsigned short* Abase = &As[(wave * 16 + lrow) * LDK + kq * 8];
    const unsigned short* Bbase = &Bs[lrow * LDK + kq * 8];
#pragma unroll
    for (int kk = 0; kk < 4; ++kk) {
        bf16x8 a = *(const bf16x8*)(Abase + kk * 32);
#pragma unroll
        for (int q = 0; q < NT; ++q) {
            bf16x8 b = *(const bf16x8*)(Bbase + q * 16 * LDK + kk * 32);
            acc[q] = __builtin_amdgcn_mfma_f32_16x16x32_bf16(a, b, acc[q], 0, 0, 0);
        }
    }

    const int rb = row0 + wave * 16 + kq * 4;
#pragma unroll
    for (int r = 0; r < 4; ++r) {
        int gr = rb + r;
        if (gr < N) {
#pragma unroll
            for (int q = 0; q < NT; q += 2) {
                int pk = __builtin_amdgcn_cvt_pk_fp8_f32(acc[q][r] * oscale,
                                                         acc[q + 1][r] * oscale, 0, false);
                C[(size_t)gr * BN + q * 16 + lrow]       = (unsigned char)(pk & 0xff);
                C[(size_t)gr * BN + (q + 1) * 16 + lrow] = (unsigned char)((pk >> 8) & 0xff);
            }
        }
    }
}

__device__ inline void dec8(uint2 v, f32x2& x0, f32x2& x1, f32x2& x2, f32x2& x3) {
    x0 += __builtin_amdgcn_cvt_pk_f32_fp8((int)v.x, false);
    x1 += __builtin_amdgcn_cvt_pk_f32_fp8((int)v.x, true);
    x2 += __builtin_amdgcn_cvt_pk_f32_fp8((int)v.y, false);
    x3 += __builtin_amdgcn_cvt_pk_f32_fp8((int)v.y, true);
}

// weighted decode: x += w * fp8(v), packed fma (same inst count as plain add)
__device__ inline void dec16w(uint4 v, f32x2 w,
                              f32x2& x0, f32x2& x1, f32x2& x2, f32x2& x3,
                              f32x2& x4, f32x2& x5, f32x2& x6, f32x2& x7) {
    x0 += w * __builtin_amdgcn_cvt_pk_f32_fp8((int)v.x, false);
    x1 += w * __builtin_amdgcn_cvt_pk_f32_fp8((int)v.x, true);
    x2 += w * __builtin_amdgcn_cvt_pk_f32_fp8((int)v.y, false);
    x3 += w * __builtin_amdgcn_cvt_pk_f32_fp8((int)v.y, true);
    x4 += w * __builtin_amdgcn_cvt_pk_f32_fp8((int)v.z, false);
    x5 += w * __builtin_amdgcn_cvt_pk_f32_fp8((int)v.z, true);
    x6 += w * __builtin_amdgcn_cvt_pk_f32_fp8((int)v.w, false);
    x7 += w * __builtin_amdgcn_cvt_pk_f32_fp8((int)v.w, true);
}

// ---------------- fused gather1 + layer-2 GEMM ----------------
// 512 threads / 64 nodes per block, one 8-lane octet per node. hs1 rows are UNSCALED;
// per-edge weight w = dinv[src] applied via packed fma during decode.

__global__ __launch_bounds__(512, 8) void fuse2_k(const unsigned char* __restrict__ hs,
                                                  const int* __restrict__ off,
                                                  const int* __restrict__ srcs,
                                                  const float* __restrict__ dinv,
                                                  const float* __restrict__ b1,
                                                  const unsigned short* __restrict__ Bt,
                                                  unsigned char* __restrict__ C,
                                                  int N) {
    constexpr int LDK = DIN + 8;
    __shared__ unsigned short As[64 * LDK];
    __shared__ unsigned short Bs[NCLS * LDK];
    const int tid  = threadIdx.x;
    const int row0 = blockIdx.x * 64;

    for (int idx = tid; idx < NCLS * 16; idx += 512) {
        int n = idx >> 4, c = (idx & 15) << 3;
        *(uint4*)&Bs[n * LDK + c] = *(const uint4*)&Bt[n * DIN + c];
    }

    // ---- phase 1: octet-per-node weighted gather into As ----
    const int oc = tid >> 3;           // octet 0..63 == As row
    const int sl = tid & 7;            // covers fp8 cols 16*sl .. 16*sl+15
    const int node = row0 + oc;
    const uint4* hp = (const uint4*)hs;  // hs1 row = 8 x uint4

    if (node < N) {
        const int beg = off[node], end = off[node + 1];
        f32x2 a0={0.f,0.f},a1={0.f,0.f},a2={0.f,0.f},a3={0.f,0.f};
        f32x2 a4={0.f,0.f},a5={0.f,0.f},a6={0.f,0.f},a7={0.f,0.f};
        int i = beg;
        for (; i + 3 < end; i += 4) {
            unsigned s0 = (unsigned)srcs[i],     s1 = (unsigned)srcs[i + 1];
            unsigned s2 = (unsigned)srcs[i + 2], s3 = (unsigned)srcs[i + 3];
            float w0 = dinv[s0], w1 = dinv[s1], w2 = dinv[s2], w3 = dinv[s3];
            uint4 v0 = hp[s0 * 8u + sl];
            uint4 v1 = hp[s1 * 8u + sl];
            uint4 v2 = hp[s2 * 8u + sl];
            uint4 v3 = hp[s3 * 8u + sl];
            dec16w(v0, (f32x2){w0,w0}, a0,a1,a2,a3,a4,a5,a6,a7);
            dec16w(v1, (f32x2){w1,w1}, a0,a1,a2,a3,a4,a5,a6,a7);
            dec16w(v2, (f32x2){w2,w2}, a0,a1,a2,a3,a4,a5,a6,a7);
            dec16w(v3, (f32x2){w3,w3}, a0,a1,a2,a3,a4,a5,a6,a7);
        }
        for (; i < end; ++i) {
            unsigned s = (unsigned)srcs[i];
            float w = dinv[s];
            uint4 v = hp[s * 8u + sl];
            dec16w(v, (f32x2){w,w}, a0,a1,a2,a3,a4,a5,a6,a7);
        }
        {   // self-loop
            float w = dinv[node];
            uint4 v = hp[(unsigned)node * 8u + sl];
            dec16w(v, (f32x2){w,w}, a0,a1,a2,a3,a4,a5,a6,a7);
        }
        const float d = dinv[node] * (1.0f / SCALE1);
        const float4 w0 = ((const float4*)b1)[sl * 4 + 0];
        const float4 w1 = ((const float4*)b1)[sl * 4 + 1];
        const float4 w2 = ((const float4*)b1)[sl * 4 + 2];
        const float4 w3 = ((const float4*)b1)[sl * 4 + 3];
        float o0  = fmaxf(fmaf(d, a0.x, w0.x), 0.f);
        float o1  = fmaxf(fmaf(d, a0.y, w0.y), 0.f);
        float o2  = fmaxf(fmaf(d, a1.x, w0.z), 0.f);
        float o3  = fmaxf(fmaf(d, a1.y, w0.w), 0.f);
        float o4  = fmaxf(fmaf(d, a2.x, w1.x), 0.f);
        float o5  = fmaxf(fmaf(d, a2.y, w1.y), 0.f);
        float o6  = fmaxf(fmaf(d, a3.x, w1.z), 0.f);
        float o7  = fmaxf(fmaf(d, a3.y, w1.w), 0.f);
        float o8  = fmaxf(fmaf(d, a4.x, w2.x), 0.f);
        float o9  = fmaxf(fmaf(d, a4.y, w2.y), 0.f);
        float o10 = fmaxf(fmaf(d, a5.x, w2.z), 0.f);
        float o11 = fmaxf(fmaf(d, a5.y, w2.w), 0.f);
        float o12 = fmaxf(fmaf(d, a6.x, w3.x), 0.f);
        float o13 = fmaxf(fmaf(d, a6.y, w3.y), 0.f);
        float o14 = fmaxf(fmaf(d, a7.x, w3.z), 0.f);
        float o15 = fmaxf(fmaf(d, a7.y, w3.w), 0.f);
        uint4 u0, u1;
        u0.x = (unsigned)f2bf(o0)  | ((unsigned)f2bf(o1)  << 16);
        u0.y = (unsigned)f2bf(o2)  | ((unsigned)f2bf(o3)  << 16);
        u0.z = (unsigned)f2bf(o4)  | ((unsigned)f2bf(o5)  << 16);
        u0.w = (unsigned)f2bf(o6)  | ((unsigned)f2bf(o7)  << 16);
        u1.x = (unsigned)f2bf(o8)  | ((unsigned)f2bf(o9)  << 16);
        u1.y = (unsigned)f2bf(o10) | ((unsigned)f2bf(o11) << 16);
        u1.z = (unsigned)f2bf(o12) | ((unsigned)f2bf(o13) << 16);
        u1.w = (unsigned)f2bf(o14) | ((unsigned)f2bf(o15) << 16);
        *(uint4*)&As[oc * LDK + sl * 16]     = u0;
        *(uint4*)&As[oc * LDK + sl * 16 + 8] = u1;
    } else {
        uint4 z = make_uint4(0, 0, 0, 0);
        *(uint4*)&As[oc * LDK + sl * 16]     = z;
        *(uint4*)&As[oc * LDK + sl * 16 + 8] = z;
    }
    __syncthreads();

    // ---- phase 2: As[64x128] @ Bs^T[128x64] -> fp8 C ----
    const int wave = tid >> 6, lane = tid & 63;
    const int ws = wave & 3;           // row stripe (16 rows)
    const int ch = wave >> 2;          // col half (32 cols)
    const int lrow = lane & 15, kq = lane >> 4;
    f32x4 acc0 = (f32x4){0.f,0.f,0.f,0.f};
    f32x4 acc1 = (f32x4){0.f,0.f,0.f,0.f};

    const unsigned short* Abase = &As[(ws * 16 + lrow) * LDK + kq * 8];
    const unsigned short* Bbase = &Bs[(ch * 32 + lrow) * LDK + kq * 8];
#pragma unroll
    for (int kk = 0; kk < 4; ++kk) {
        bf16x8 a  = *(const bf16x8*)(Abase + kk * 32);
        bf16x8 b0 = *(const bf16x8*)(Bbase + kk * 32);
        bf16x8 b1v= *(const bf16x8*)(Bbase + 16 * LDK + kk * 32);
        acc0 = __builtin_amdgcn_mfma_f32_16x16x32_bf16(a, b0,  acc0, 0, 0, 0);
        acc1 = __builtin_amdgcn_mfma_f32_16x16x32_bf16(a, b1v, acc1, 0, 0, 0);
    }

    const int rb = row0 + ws * 16 + kq * 4;
#pragma unroll
    for (int r = 0; r < 4; ++r) {
        int gr = rb + r;
        if (gr < N) {
            float sc2 = dinv[gr] * SCALE2;
            int pk = __builtin_amdgcn_cvt_pk_fp8_f32(acc0[r] * sc2, acc1[r] * sc2, 0, false);
            C[(size_t)gr * NCLS + ch * 32 + lrow]      = (unsigned char)(pk & 0xff);
            C[(size_t)gr * NCLS + ch * 32 + 16 + lrow] = (unsigned char)((pk >> 8) & 0xff);
        }
    }
}

// ---------------- gather layer 2 + log_softmax (fp8 in) ----------------
// one 8-lane octet owns one node; lane sl covers cols 8*sl..8*sl+7. unroll 8.

__global__ __launch_bounds__(256) void gather2_k(const unsigned char* __restrict__ hs,
                                                 const int* __restrict__ off,
                                                 const int* __restrict__ srcs,
                                                 const float* __restrict__ dinv,
                                                 const float* __restrict__ b2,
                                                 float* __restrict__ out, int N) {
    const int lane = threadIdx.x & 63;
    const int wave = threadIdx.x >> 6;
    const int o8 = lane >> 3;          // octet 0..7 -> node within wave
    const int sl = lane & 7;           // covers cols 8*sl..8*sl+7
    const int node = blockIdx.x * 32 + wave * 8 + o8;
    if (node >= N) return;
    const int beg = off[node], end = off[node + 1];
    const uint2* hp = (const uint2*)hs;            // row = 8 x uint2
    f32x2 A0 = {0.f,0.f}, A1 = {0.f,0.f}, A2 = {0.f,0.f}, A3 = {0.f,0.f};
    f32x2 C0 = {0.f,0.f}, C1 = {0.f,0.f}, C2 = {0.f,0.f}, C3 = {0.f,0.f};
    int i = beg;
    for (; i + 7 < end; i += 8) {
        unsigned s0 = (unsigned)srcs[i],     s1 = (unsigned)srcs[i + 1];
        unsigned s2 = (unsigned)srcs[i + 2], s3 = (unsigned)srcs[i + 3];
        unsigned s4 = (unsigned)srcs[i + 4], s5 = (unsigned)srcs[i + 5];
        unsigned s6 = (unsigned)srcs[i + 6], s7 = (unsigned)srcs[i + 7];
        uint2 v0 = hp[s0 * 8u + sl];
        uint2 v1 = hp[s1 * 8u + sl];
        uint2 v2 = hp[s2 * 8u + sl];
        uint2 v3 = hp[s3 * 8u + sl];
        uint2 v4 = hp[s4 * 8u + sl];
        uint2 v5 = hp[s5 * 8u + sl];
        uint2 v6 = hp[s6 * 8u + sl];
        uint2 v7 = hp[s7 * 8u + sl];
        dec8(v0, A0, A1, A2, A3);
        dec8(v1, C0, C1, C2, C3);
        dec8(v2, A0, A1, A2, A3);
        dec8(v3, C0, C1, C2, C3);
        dec8(v4, A0, A1, A2, A3);
        dec8(v5, C0, C1, C2, C3);
        dec8(v6, A0, A1, A2, A3);
        dec8(v7, C0, C1, C2, C3);
    }
    for (; i + 3 < end; i += 4) {
        unsigned s0 = (unsigned)srcs[i],     s1 = (unsigned)srcs[i + 1];
        unsigned s2 = (unsigned)srcs[i + 2], s3 = (unsigned)srcs[i + 3];
        uint2 v0 = hp[s0 * 8u + sl];
        uint2 v1 = hp[s1 * 8u + sl];
        uint2 v2 = hp[s2 * 8u + sl];
        uint2 v3 = hp[s3 * 8u + sl];
        dec8(v0, A0, A1, A2, A3);
        dec8(v1, C0, C1, C2, C3);
        dec8(v2, A0, A1, A2, A3);
        dec8(v3, C0, C1, C2, C3);
    }
    for (; i < end; ++i) {
        uint2 v = hp[(unsigned)srcs[i] * 8u + sl];
        dec8(v, A0, A1, A2, A3);
    }
    {   // self-loop
        uint2 v = hp[(unsigned)node * 8u + sl];
        dec8(v, C0, C1, C2, C3);
    }
    A0 += C0; A1 += C1; A2 += C2; A3 += C3;

    float d = dinv[node] * (1.0f / SCALE2);
    float4 ba = ((const float4*)b2)[sl * 2];
    float4 bb = ((const float4*)b2)[sl * 2 + 1];
    float v0 = fmaf(d, A0.x, ba.x);
    float v1 = fmaf(d, A0.y, ba.y);
    float v2 = fmaf(d, A1.x, ba.z);
    float v3 = fmaf(d, A1.y, ba.w);
    float v4 = fmaf(d, A2.x, bb.x);
    float v5 = fmaf(d, A2.y, bb.y);
    float v6 = fmaf(d, A3.x, bb.z);
    float v7 = fmaf(d, A3.y, bb.w);
    float m = fmaxf(fmaxf(fmaxf(v0, v1), fmaxf(v2, v3)), fmaxf(fmaxf(v4, v5), fmaxf(v6, v7)));
#pragma unroll
    for (int mk = 1; mk <= 4; mk <<= 1) m = fmaxf(m, __shfl_xor(m, mk, 64));
    float s = __expf(v0 - m) + __expf(v1 - m) + __expf(v2 - m) + __expf(v3 - m)
            + __expf(v4 - m) + __expf(v5 - m) + __expf(v6 - m) + __expf(v7 - m);
#pragma unroll
    for (int mk = 1; mk <= 4; mk <<= 1) s += __shfl_xor(s, mk, 64);
    float ls = m + __logf(s);
    float4 oa, ob;
    oa.x = v0 - ls; oa.y = v1 - ls; oa.z = v2 - ls; oa.w = v3 - ls;
    ob.x = v4 - ls; ob.y = v5 - ls; ob.z = v6 - ls; ob.w = v7 - ls;
    ((float4*)out)[(unsigned)node * 16u + sl * 2]     = oa;
    ((float4*)out)[(unsigned)node * 16u + sl * 2 + 1] = ob;
}

// ---------------- launch ----------------

extern "C" void kernel_launch(void* const* d_in, const int* in_sizes, int n_in,
                              void* d_out, int out_size, void* d_ws, size_t ws_size,
                              hipStream_t stream) {
    const float* x  = (const float*)d_in[0];
    const int*   ei = (const int*)d_in[1];
    const float* W1 = (const float*)d_in[2];
    const float* b1 = (const float*)d_in[3];
    const float* W2 = (const float*)d_in[4];
    const float* b2 = (const float*)d_in[5];
    float* out = (float*)d_out;

    const int N  = in_sizes[0] / DIN;
    const int E  = in_sizes[1] / 2;
    const int NB = (N + BSZ - 1) >> BSH;     // 391
    const int NG = (N + 63) / 64;            // 1563 mgemm blocks

    char* p = (char*)d_ws;
    auto alloc = [&](size_t bytes) { void* r = p; p += (bytes + 255) & ~(size_t)255; return r; };
    float* dinv  = (float*)alloc((size_t)N * 4);
    int*   gcnt  = (int*)  alloc((size_t)NB * 4);
    int*   bbase = (int*)  alloc((size_t)NB * 4);
    int*   off   = (int*)  alloc((size_t)(N + 1) * 4);
    int*   srcs  = (int*)  alloc((size_t)E * 4);
    unsigned int* tmp = (unsigned int*)alloc((size_t)NB * BCAP * 4);
    unsigned short* wt1 = (unsigned short*)alloc(128 * 128 * 2);
    unsigned short* wt2 = (unsigned short*)alloc(64 * 128 * 2);
    unsigned char*  hs1 = (unsigned char*)alloc((size_t)N * DIN);   // fp8
    unsigned char*  hs2 = (unsigned char*)alloc((size_t)N * NCLS);  // fp8

    wprep_k<<<64, 256, 0, stream>>>(W1, W2, wt1, wt2, gcnt, NB);
    binA_k<<<(E + 4095) / 4096, 1024, 0, stream>>>(ei, gcnt, tmp, E, NB);
    scanb_k<<<1, 512, 0, stream>>>(gcnt, bbase, NB);
    bmix_k<<<NB + NG, 256, 0, stream>>>(tmp, gcnt, bbase, off, dinv, srcs, N, E, NB,
                                        x, wt1, hs1, SCALE1);
    fuse2_k<<<(N + 63) / 64, 512, 0, stream>>>(hs1, off, srcs, dinv, b1, wt2, hs2, N);
    gather2_k<<<(N + 31) / 32, 256, 0, stream>>>(hs2, off, srcs, dinv, b2, out, N);
}

// Round 12
// 199.834 us; speedup vs baseline: 2.0381x; 1.0139x over previous
//
#include <hip/hip_runtime.h>
#include <math.h>

#define DIN 128   // D_IN == D_HID == 128
#define NCLS 64
#define BSH  8    // log2(bucket size): 256 dst-nodes per bucket
#define BSZ  256
#define BCAP 5120 // per-bucket capacity: mean 4096, sd ~64 -> +16 sigma
#define SCALE1 64.0f   // hs1 fp8 scale
#define SCALE2 256.0f  // hs2 fp8 scale

typedef __attribute__((ext_vector_type(4))) float  f32x4;
typedef __attribute__((ext_vector_type(2))) float  f32x2;
typedef __attribute__((ext_vector_type(8))) short  bf16x8;   // MFMA A/B frag (4 VGPRs)

__device__ inline unsigned short f2bf(float f) {             // round-to-nearest-even
    unsigned int u = __float_as_uint(f);
    u += 0x7fff + ((u >> 16) & 1);
    return (unsigned short)(u >> 16);
}

// ---------------- W prep: transpose + cast to bf16; zero gcnt ----------------

__global__ __launch_bounds__(256) void wprep_k(const float* __restrict__ W1,
                                               const float* __restrict__ W2,
                                               unsigned short* __restrict__ wt1,
                                               unsigned short* __restrict__ wt2,
                                               int* __restrict__ gcnt, int NB) {
    int i = blockIdx.x * 256 + threadIdx.x;
    if (i < 128 * 128) { int k = i >> 7, n = i & 127; wt1[n * 128 + k] = f2bf(W1[i]); }
    if (i < 128 * 64)  { int k = i >> 6, n = i & 63;  wt2[n * 128 + k] = f2bf(W2[i]); }
    if (i < NB)        gcnt[i] = 0;
}

// ---------------- CSR build phase A: bucket sort with COALESCED tmp writes ----------------
// r10 lesson: scattered 4B stores -> 9x write amplification, occupancy-independent.
// Block-sort edges in LDS by bucket, record global slots (consecutive per bucket run),
// write in sorted order -> coalesced bursts.

__global__ __launch_bounds__(1024) void binA_k(const int* __restrict__ ei,
                                               int* __restrict__ gcnt,
                                               unsigned int* __restrict__ tmp,
                                               int E, int NB) {
    __shared__ unsigned int spk[4096];   // packed edges, sorted by bucket
    __shared__ unsigned int sgp[4096];   // global tmp index per sorted edge
    __shared__ int lcnt[512], sbase[512], gpos[512];
    const int t = threadIdx.x;
    for (int i = t; i < 512; i += 1024) lcnt[i] = 0;
    __syncthreads();

    const int base = blockIdx.x * 4096;
    unsigned int pk[4];
    short bk[4], rk[4];
#pragma unroll
    for (int k = 0; k < 4; ++k) {
        int e = base + k * 1024 + t;
        if (e < E) {
            int s = ei[e];
            int d = ei[E + e];
            int b = d >> BSH;
            pk[k] = ((unsigned int)s << BSH) | (unsigned int)(d & (BSZ - 1));
            bk[k] = (short)b;
            rk[k] = (short)atomicAdd(&lcnt[b], 1);
        } else {
            bk[k] = -1;
        }
    }
    __syncthreads();
    if (t < 512) sbase[t] = lcnt[t];
    __syncthreads();
    for (int o = 1; o < 512; o <<= 1) {           // inclusive scan over 512 buckets
        int x = 0;
        if (t < 512 && t >= o) x = sbase[t - o];
        __syncthreads();
        if (t < 512) sbase[t] += x;
        __syncthreads();
    }
    if (t < NB) gpos[t] = lcnt[t] ? atomicAdd(&gcnt[t], lcnt[t]) : 0;
    __syncthreads();
#pragma unroll
    for (int k = 0; k < 4; ++k) {
        if (bk[k] >= 0) {
            int b = bk[k];
            int j = sbase[b] - lcnt[b] + rk[k];   // block-local sorted slot
            int p = gpos[b] + rk[k];              // slot within bucket's global region
            spk[j] = pk[k];
            sgp[j] = (p < BCAP) ? ((unsigned int)b * BCAP + (unsigned int)p) : 0xFFFFFFFFu;
        }
    }
    __syncthreads();
    const int cnt = min(4096, E - base);
    for (int j = t; j < cnt; j += 1024) {         // sorted order -> coalesced bursts
        unsigned int g = sgp[j];
        if (g != 0xFFFFFFFFu) tmp[g] = spk[j];
    }
}

// ---------------- bmix: binB (blocks < NB) || layer-1 MFMA GEMM ----------------
// binB: computes its own bucket base by reducing gcnt[0..b) (scanb dispatch deleted),
// then per-bucket counting sort by dst&255 -> CSR srcs + off + dinv.
// mgemm: BM=64, BN=128, fp32 A -> bf16 LDS -> MFMA -> fp8 UNSCALED (dinv applied
// per-edge in fuse2). LDS overlaid in one 52224B array (binB uses 25.6KB).

__global__ __launch_bounds__(256) void bmix_k(const unsigned int* __restrict__ tmp,
                                              const int* __restrict__ gcnt,
                                              int* __restrict__ off,
                                              float* __restrict__ dinv,
                                              int* __restrict__ srcs,
                                              int N, int E, int NB,
                                              const float* __restrict__ A,
                                              const unsigned short* __restrict__ Bt,
                                              unsigned char* __restrict__ C,
                                              float oscale) {
    constexpr int LDK = DIN + 8;
    constexpr int BN  = 128;
    __shared__ __align__(16) unsigned char raw[64 * LDK * 2 + BN * LDK * 2]; // 52224 B
    const int t = threadIdx.x;

    if ((int)blockIdx.x < NB) {
        // ---- binB path (25.6 KB of raw) ----
        unsigned int* stg  = (unsigned int*)raw;               // BCAP u32 = 20480 B
        int* lcnt = (int*)(raw + BCAP * 4);                    // 256 ints each
        int* sc   = lcnt + BSZ;
        int* loff = sc + BSZ;
        int* lcur = loff + BSZ;
        int* red  = lcur + BSZ;                                // 256 ints (scan fold)
        const int b = blockIdx.x;
        int cnt = gcnt[b];
        if (cnt > BCAP) cnt = BCAP;
        lcnt[t] = 0; lcur[t] = 0;
        // bucket base = sum of gcnt[0..b) (replaces the scanb dispatch)
        int partial = 0;
        for (int j = t; j < b; j += 256) partial += gcnt[j];
        red[t] = partial;
        __syncthreads();
        for (int o = 128; o > 0; o >>= 1) {
            if (t < o) red[t] += red[t + o];
            __syncthreads();
        }
        const int base = red[0];
        for (int i = t; i < cnt; i += 256) {
            unsigned int v = tmp[(size_t)b * BCAP + i];
            stg[i] = v;
            atomicAdd(&lcnt[v & (BSZ - 1u)], 1);
        }
        __syncthreads();
        sc[t] = lcnt[t];
        __syncthreads();
        for (int o = 1; o < BSZ; o <<= 1) {
            int x = (t >= o) ? sc[t - o] : 0;
            __syncthreads();
            sc[t] += x;
            __syncthreads();
        }
        int excl = (t == 0) ? 0 : sc[t - 1];
        loff[t] = excl;
        int node = b * BSZ + t;
        if (node <= N) off[node] = base + excl;
        if (node < N)  dinv[node] = rsqrtf(1.0f + (float)lcnt[t]);
        __syncthreads();
        for (int i = t; i < cnt; i += 256) {
            unsigned int v = stg[i];
            int l = v & (BSZ - 1u);
            int r = atomicAdd(&lcur[l], 1);
            srcs[base + loff[l] + r] = (int)(v >> BSH);
        }
        return;
    }

    // ---- mgemm path: hs1 = fp8(oscale * (x@W1)), no per-row scale ----
    unsigned short* As = (unsigned short*)raw;                 // 64 x LDK
    unsigned short* Bs = As + 64 * LDK;                        // BN x LDK
    const int row0 = ((int)blockIdx.x - NB) * 64;

    for (int idx = t; idx < BN * 16; idx += 256) {
        int n = idx >> 4, c = (idx & 15) << 3;
        *(uint4*)&Bs[n * LDK + c] = *(const uint4*)&Bt[n * DIN + c];
    }
    for (int idx = t; idx < 64 * 16; idx += 256) {
        int r = idx >> 4, c = (idx & 15) << 3;
        int gr = row0 + r;
        unsigned short v[8];
        if (gr < N) {
            f32x4 a0 = *(const f32x4*)&A[(size_t)gr * DIN + c];
            f32x4 a1 = *(const f32x4*)&A[(size_t)gr * DIN + c + 4];
            v[0] = f2bf(a0.x); v[1] = f2bf(a0.y); v[2] = f2bf(a0.z); v[3] = f2bf(a0.w);
            v[4] = f2bf(a1.x); v[5] = f2bf(a1.y); v[6] = f2bf(a1.z); v[7] = f2bf(a1.w);
        } else {
#pragma unroll
            for (int j = 0; j < 8; ++j) v[j] = 0;
        }
        *(uint4*)&As[r * LDK + c] = *(const uint4*)v;
    }
    __syncthreads();

    const int wave = t >> 6, lane = t & 63;
    const int lrow = lane & 15, kq = lane >> 4;
    constexpr int NT = BN / 16;
    f32x4 acc[NT];
#pragma unroll
    for (int q = 0; q < NT; ++q) acc[q] = (f32x4){0.f, 0.f, 0.f, 0.f};

    const unsigned short* Abase = &As[(wave * 16 + lrow) * LDK + kq * 8];
    const unsigned short* Bbase = &Bs[lrow * LDK + kq * 8];
#pragma unroll
    for (int kk = 0; kk < 4; ++kk) {
        bf16x8 a = *(const bf16x8*)(Abase + kk * 32);
#pragma unroll
        for (int q = 0; q < NT; ++q) {
            bf16x8 b = *(const bf16x8*)(Bbase + q * 16 * LDK + kk * 32);
            acc[q] = __builtin_amdgcn_mfma_f32_16x16x32_bf16(a, b, acc[q], 0, 0, 0);
        }
    }

    const int rb = row0 + wave * 16 + kq * 4;
#pragma unroll
    for (int r = 0; r < 4; ++r) {
        int gr = rb + r;
        if (gr < N) {
#pragma unroll
            for (int q = 0; q < NT; q += 2) {
                int pk = __builtin_amdgcn_cvt_pk_fp8_f32(acc[q][r] * oscale,
                                                         acc[q + 1][r] * oscale, 0, false);
                C[(size_t)gr * BN + q * 16 + lrow]       = (unsigned char)(pk & 0xff);
                C[(size_t)gr * BN + (q + 1) * 16 + lrow] = (unsigned char)((pk >> 8) & 0xff);
            }
        }
    }
}

__device__ inline void dec8(uint2 v, f32x2& x0, f32x2& x1, f32x2& x2, f32x2& x3) {
    x0 += __builtin_amdgcn_cvt_pk_f32_fp8((int)v.x, false);
    x1 += __builtin_amdgcn_cvt_pk_f32_fp8((int)v.x, true);
    x2 += __builtin_amdgcn_cvt_pk_f32_fp8((int)v.y, false);
    x3 += __builtin_amdgcn_cvt_pk_f32_fp8((int)v.y, true);
}

// weighted decode: x += w * fp8(v), packed fma (same inst count as plain add)
__device__ inline void dec16w(uint4 v, f32x2 w,
                              f32x2& x0, f32x2& x1, f32x2& x2, f32x2& x3,
                              f32x2& x4, f32x2& x5, f32x2& x6, f32x2& x7) {
    x0 += w * __builtin_amdgcn_cvt_pk_f32_fp8((int)v.x, false);
    x1 += w * __builtin_amdgcn_cvt_pk_f32_fp8((int)v.x, true);
    x2 += w * __builtin_amdgcn_cvt_pk_f32_fp8((int)v.y, false);
    x3 += w * __builtin_amdgcn_cvt_pk_f32_fp8((int)v.y, true);
    x4 += w * __builtin_amdgcn_cvt_pk_f32_fp8((int)v.z, false);
    x5 += w * __builtin_amdgcn_cvt_pk_f32_fp8((int)v.z, true);
    x6 += w * __builtin_amdgcn_cvt_pk_f32_fp8((int)v.w, false);
    x7 += w * __builtin_amdgcn_cvt_pk_f32_fp8((int)v.w, true);
}

// ---------------- fused gather1 + layer-2 GEMM ----------------
// 512 threads / 64 nodes per block, one 8-lane octet per node. hs1 rows are UNSCALED;
// per-edge weight w = dinv[src] applied via packed fma during decode.

__global__ __launch_bounds__(512, 8) void fuse2_k(const unsigned char* __restrict__ hs,
                                                  const int* __restrict__ off,
                                                  const int* __restrict__ srcs,
                                                  const float* __restrict__ dinv,
                                                  const float* __restrict__ b1,
                                                  const unsigned short* __restrict__ Bt,
                                                  unsigned char* __restrict__ C,
                                                  int N) {
    constexpr int LDK = DIN + 8;
    __shared__ unsigned short As[64 * LDK];
    __shared__ unsigned short Bs[NCLS * LDK];
    const int tid  = threadIdx.x;
    const int row0 = blockIdx.x * 64;

    for (int idx = tid; idx < NCLS * 16; idx += 512) {
        int n = idx >> 4, c = (idx & 15) << 3;
        *(uint4*)&Bs[n * LDK + c] = *(const uint4*)&Bt[n * DIN + c];
    }

    // ---- phase 1: octet-per-node weighted gather into As ----
    const int oc = tid >> 3;           // octet 0..63 == As row
    const int sl = tid & 7;            // covers fp8 cols 16*sl .. 16*sl+15
    const int node = row0 + oc;
    const uint4* hp = (const uint4*)hs;  // hs1 row = 8 x uint4

    if (node < N) {
        const int beg = off[node], end = off[node + 1];
        f32x2 a0={0.f,0.f},a1={0.f,0.f},a2={0.f,0.f},a3={0.f,0.f};
        f32x2 a4={0.f,0.f},a5={0.f,0.f},a6={0.f,0.f},a7={0.f,0.f};
        int i = beg;
        for (; i + 3 < end; i += 4) {
            unsigned s0 = (unsigned)srcs[i],     s1 = (unsigned)srcs[i + 1];
            unsigned s2 = (unsigned)srcs[i + 2], s3 = (unsigned)srcs[i + 3];
            float w0 = dinv[s0], w1 = dinv[s1], w2 = dinv[s2], w3 = dinv[s3];
            uint4 v0 = hp[s0 * 8u + sl];
            uint4 v1 = hp[s1 * 8u + sl];
            uint4 v2 = hp[s2 * 8u + sl];
            uint4 v3 = hp[s3 * 8u + sl];
            dec16w(v0, (f32x2){w0,w0}, a0,a1,a2,a3,a4,a5,a6,a7);
            dec16w(v1, (f32x2){w1,w1}, a0,a1,a2,a3,a4,a5,a6,a7);
            dec16w(v2, (f32x2){w2,w2}, a0,a1,a2,a3,a4,a5,a6,a7);
            dec16w(v3, (f32x2){w3,w3}, a0,a1,a2,a3,a4,a5,a6,a7);
        }
        for (; i < end; ++i) {
            unsigned s = (unsigned)srcs[i];
            float w = dinv[s];
            uint4 v = hp[s * 8u + sl];
            dec16w(v, (f32x2){w,w}, a0,a1,a2,a3,a4,a5,a6,a7);
        }
        {   // self-loop
            float w = dinv[node];
            uint4 v = hp[(unsigned)node * 8u + sl];
            dec16w(v, (f32x2){w,w}, a0,a1,a2,a3,a4,a5,a6,a7);
        }
        const float d = dinv[node] * (1.0f / SCALE1);
        const float4 w0 = ((const float4*)b1)[sl * 4 + 0];
        const float4 w1 = ((const float4*)b1)[sl * 4 + 1];
        const float4 w2 = ((const float4*)b1)[sl * 4 + 2];
        const float4 w3 = ((const float4*)b1)[sl * 4 + 3];
        float o0  = fmaxf(fmaf(d, a0.x, w0.x), 0.f);
        float o1  = fmaxf(fmaf(d, a0.y, w0.y), 0.f);
        float o2  = fmaxf(fmaf(d, a1.x, w0.z), 0.f);
        float o3  = fmaxf(fmaf(d, a1.y, w0.w), 0.f);
        float o4  = fmaxf(fmaf(d, a2.x, w1.x), 0.f);
        float o5  = fmaxf(fmaf(d, a2.y, w1.y), 0.f);
        float o6  = fmaxf(fmaf(d, a3.x, w1.z), 0.f);
        float o7  = fmaxf(fmaf(d, a3.y, w1.w), 0.f);
        float o8  = fmaxf(fmaf(d, a4.x, w2.x), 0.f);
        float o9  = fmaxf(fmaf(d, a4.y, w2.y), 0.f);
        float o10 = fmaxf(fmaf(d, a5.x, w2.z), 0.f);
        float o11 = fmaxf(fmaf(d, a5.y, w2.w), 0.f);
        float o12 = fmaxf(fmaf(d, a6.x, w3.x), 0.f);
        float o13 = fmaxf(fmaf(d, a6.y, w3.y), 0.f);
        float o14 = fmaxf(fmaf(d, a7.x, w3.z), 0.f);
        float o15 = fmaxf(fmaf(d, a7.y, w3.w), 0.f);
        uint4 u0, u1;
        u0.x = (unsigned)f2bf(o0)  | ((unsigned)f2bf(o1)  << 16);
        u0.y = (unsigned)f2bf(o2)  | ((unsigned)f2bf(o3)  << 16);
        u0.z = (unsigned)f2bf(o4)  | ((unsigned)f2bf(o5)  << 16);
        u0.w = (unsigned)f2bf(o6)  | ((unsigned)f2bf(o7)  << 16);
        u1.x = (unsigned)f2bf(o8)  | ((unsigned)f2bf(o9)  << 16);
        u1.y = (unsigned)f2bf(o10) | ((unsigned)f2bf(o11) << 16);
        u1.z = (unsigned)f2bf(o12) | ((unsigned)f2bf(o13) << 16);
        u1.w = (unsigned)f2bf(o14) | ((unsigned)f2bf(o15) << 16);
        *(uint4*)&As[oc * LDK + sl * 16]     = u0;
        *(uint4*)&As[oc * LDK + sl * 16 + 8] = u1;
    } else {
        uint4 z = make_uint4(0, 0, 0, 0);
        *(uint4*)&As[oc * LDK + sl * 16]     = z;
        *(uint4*)&As[oc * LDK + sl * 16 + 8] = z;
    }
    __syncthreads();

    // ---- phase 2: As[64x128] @ Bs^T[128x64] -> fp8 C ----
    const int wave = tid >> 6, lane = tid & 63;
    const int ws = wave & 3;           // row stripe (16 rows)
    const int ch = wave >> 2;          // col half (32 cols)
    const int lrow = lane & 15, kq = lane >> 4;
    f32x4 acc0 = (f32x4){0.f,0.f,0.f,0.f};
    f32x4 acc1 = (f32x4){0.f,0.f,0.f,0.f};

    const unsigned short* Abase = &As[(ws * 16 + lrow) * LDK + kq * 8];
    const unsigned short* Bbase = &Bs[(ch * 32 + lrow) * LDK + kq * 8];
#pragma unroll
    for (int kk = 0; kk < 4; ++kk) {
        bf16x8 a  = *(const bf16x8*)(Abase + kk * 32);
        bf16x8 b0 = *(const bf16x8*)(Bbase + kk * 32);
        bf16x8 b1v= *(const bf16x8*)(Bbase + 16 * LDK + kk * 32);
        acc0 = __builtin_amdgcn_mfma_f32_16x16x32_bf16(a, b0,  acc0, 0, 0, 0);
        acc1 = __builtin_amdgcn_mfma_f32_16x16x32_bf16(a, b1v, acc1, 0, 0, 0);
    }

    const int rb = row0 + ws * 16 + kq * 4;
#pragma unroll
    for (int r = 0; r < 4; ++r) {
        int gr = rb + r;
        if (gr < N) {
            float sc2 = dinv[gr] * SCALE2;
            int pk = __builtin_amdgcn_cvt_pk_fp8_f32(acc0[r] * sc2, acc1[r] * sc2, 0, false);
            C[(size_t)gr * NCLS + ch * 32 + lrow]      = (unsigned char)(pk & 0xff);
            C[(size_t)gr * NCLS + ch * 32 + 16 + lrow] = (unsigned char)((pk >> 8) & 0xff);
        }
    }
}

// ---------------- gather layer 2 + log_softmax (fp8 in) ----------------
// one 8-lane octet owns one node; lane sl covers cols 8*sl..8*sl+7. unroll 8.
// out stores are nontemporal (never re-read; keeps hs2 resident in L2).

__global__ __launch_bounds__(256) void gather2_k(const unsigned char* __restrict__ hs,
                                                 const int* __restrict__ off,
                                                 const int* __restrict__ srcs,
                                                 const float* __restrict__ dinv,
                                                 const float* __restrict__ b2,
                                                 float* __restrict__ out, int N) {
    const int lane = threadIdx.x & 63;
    const int wave = threadIdx.x >> 6;
    const int o8 = lane >> 3;          // octet 0..7 -> node within wave
    const int sl = lane & 7;           // covers cols 8*sl..8*sl+7
    const int node = blockIdx.x * 32 + wave * 8 + o8;
    if (node >= N) return;
    const int beg = off[node], end = off[node + 1];
    const uint2* hp = (const uint2*)hs;            // row = 8 x uint2
    f32x2 A0 = {0.f,0.f}, A1 = {0.f,0.f}, A2 = {0.f,0.f}, A3 = {0.f,0.f};
    f32x2 C0 = {0.f,0.f}, C1 = {0.f,0.f}, C2 = {0.f,0.f}, C3 = {0.f,0.f};
    int i = beg;
    for (; i + 7 < end; i += 8) {
        unsigned s0 = (unsigned)srcs[i],     s1 = (unsigned)srcs[i + 1];
        unsigned s2 = (unsigned)srcs[i + 2], s3 = (unsigned)srcs[i + 3];
        unsigned s4 = (unsigned)srcs[i + 4], s5 = (unsigned)srcs[i + 5];
        unsigned s6 = (unsigned)srcs[i + 6], s7 = (unsigned)srcs[i + 7];
        uint2 v0 = hp[s0 * 8u + sl];
        uint2 v1 = hp[s1 * 8u + sl];
        uint2 v2 = hp[s2 * 8u + sl];
        uint2 v3 = hp[s3 * 8u + sl];
        uint2 v4 = hp[s4 * 8u + sl];
        uint2 v5 = hp[s5 * 8u + sl];
        uint2 v6 = hp[s6 * 8u + sl];
        uint2 v7 = hp[s7 * 8u + sl];
        dec8(v0, A0, A1, A2, A3);
        dec8(v1, C0, C1, C2, C3);
        dec8(v2, A0, A1, A2, A3);
        dec8(v3, C0, C1, C2, C3);
        dec8(v4, A0, A1, A2, A3);
        dec8(v5, C0, C1, C2, C3);
        dec8(v6, A0, A1, A2, A3);
        dec8(v7, C0, C1, C2, C3);
    }
    for (; i + 3 < end; i += 4) {
        unsigned s0 = (unsigned)srcs[i],     s1 = (unsigned)srcs[i + 1];
        unsigned s2 = (unsigned)srcs[i + 2], s3 = (unsigned)srcs[i + 3];
        uint2 v0 = hp[s0 * 8u + sl];
        uint2 v1 = hp[s1 * 8u + sl];
        uint2 v2 = hp[s2 * 8u + sl];
        uint2 v3 = hp[s3 * 8u + sl];
        dec8(v0, A0, A1, A2, A3);
        dec8(v1, C0, C1, C2, C3);
        dec8(v2, A0, A1, A2, A3);
        dec8(v3, C0, C1, C2, C3);
    }
    for (; i < end; ++i) {
        uint2 v = hp[(unsigned)srcs[i] * 8u + sl];
        dec8(v, A0, A1, A2, A3);
    }
    {   // self-loop
        uint2 v = hp[(unsigned)node * 8u + sl];
        dec8(v, C0, C1, C2, C3);
    }
    A0 += C0; A1 += C1; A2 += C2; A3 += C3;

    float d = dinv[node] * (1.0f / SCALE2);
    float4 ba = ((const float4*)b2)[sl * 2];
    float4 bb = ((const float4*)b2)[sl * 2 + 1];
    float v0 = fmaf(d, A0.x, ba.x);
    float v1 = fmaf(d, A0.y, ba.y);
    float v2 = fmaf(d, A1.x, ba.z);
    float v3 = fmaf(d, A1.y, ba.w);
    float v4 = fmaf(d, A2.x, bb.x);
    float v5 = fmaf(d, A2.y, bb.y);
    float v6 = fmaf(d, A3.x, bb.z);
    float v7 = fmaf(d, A3.y, bb.w);
    float m = fmaxf(fmaxf(fmaxf(v0, v1), fmaxf(v2, v3)), fmaxf(fmaxf(v4, v5), fmaxf(v6, v7)));
#pragma unroll
    for (int mk = 1; mk <= 4; mk <<= 1) m = fmaxf(m, __shfl_xor(m, mk, 64));
    float s = __expf(v0 - m) + __expf(v1 - m) + __expf(v2 - m) + __expf(v3 - m)
            + __expf(v4 - m) + __expf(v5 - m) + __expf(v6 - m) + __expf(v7 - m);
#pragma unroll
    for (int mk = 1; mk <= 4; mk <<= 1) s += __shfl_xor(s, mk, 64);
    float ls = m + __logf(s);
    f32x4 oa = (f32x4){v0 - ls, v1 - ls, v2 - ls, v3 - ls};
    f32x4 ob = (f32x4){v4 - ls, v5 - ls, v6 - ls, v7 - ls};
    f32x4* outp = (f32x4*)out;
    __builtin_nontemporal_store(oa, &outp[(unsigned)node * 16u + sl * 2]);
    __builtin_nontemporal_store(ob, &outp[(unsigned)node * 16u + sl * 2 + 1]);
}

// ---------------- launch ----------------

extern "C" void kernel_launch(void* const* d_in, const int* in_sizes, int n_in,
                              void* d_out, int out_size, void* d_ws, size_t ws_size,
                              hipStream_t stream) {
    const float* x  = (const float*)d_in[0];
    const int*   ei = (const int*)d_in[1];
    const float* W1 = (const float*)d_in[2];
    const float* b1 = (const float*)d_in[3];
    const float* W2 = (const float*)d_in[4];
    const float* b2 = (const float*)d_in[5];
    float* out = (float*)d_out;

    const int N  = in_sizes[0] / DIN;
    const int E  = in_sizes[1] / 2;
    const int NB = (N + BSZ - 1) >> BSH;     // 391
    const int NG = (N + 63) / 64;            // 1563 mgemm blocks

    char* p = (char*)d_ws;
    auto alloc = [&](size_t bytes) { void* r = p; p += (bytes + 255) & ~(size_t)255; return r; };
    float* dinv  = (float*)alloc((size_t)N * 4);
    int*   gcnt  = (int*)  alloc((size_t)NB * 4);
    int*   off   = (int*)  alloc((size_t)(N + 1) * 4);
    int*   srcs  = (int*)  alloc((size_t)E * 4);
    unsigned int* tmp = (unsigned int*)alloc((size_t)NB * BCAP * 4);
    unsigned short* wt1 = (unsigned short*)alloc(128 * 128 * 2);
    unsigned short* wt2 = (unsigned short*)alloc(64 * 128 * 2);
    unsigned char*  hs1 = (unsigned char*)alloc((size_t)N * DIN);   // fp8
    unsigned char*  hs2 = (unsigned char*)alloc((size_t)N * NCLS);  // fp8

    wprep_k<<<64, 256, 0, stream>>>(W1, W2, wt1, wt2, gcnt, NB);
    binA_k<<<(E + 4095) / 4096, 1024, 0, stream>>>(ei, gcnt, tmp, E, NB);
    bmix_k<<<NB + NG, 256, 0, stream>>>(tmp, gcnt, off, dinv, srcs, N, E, NB,
                                        x, wt1, hs1, SCALE1);
    fuse2_k<<<(N + 63) / 64, 512, 0, stream>>>(hs1, off, srcs, dinv, b1, wt2, hs2, N);
    gather2_k<<<(N + 31) / 32, 256, 0, stream>>>(hs2, off, srcs, dinv, b2, out, N);
}